// Round 6
// baseline (1035.217 us; speedup 1.0000x reference)
//
#include <hip/hip_runtime.h>

typedef unsigned short u16;
typedef __attribute__((ext_vector_type(8))) short bf16x8;   // 8 bf16 (4 VGPRs)
typedef __attribute__((ext_vector_type(4))) float f32x4;
typedef __attribute__((ext_vector_type(4))) unsigned int uint4v;
typedef __attribute__((ext_vector_type(4))) unsigned short us4;

#define NLAYER 6
#define D_MODEL 512
#define NHEAD 8
#define DKH 64
#define SEQ 1024
#define BATCH 8
#define FFN 2048
#define MROWS (BATCH * SEQ)  /* 8192 */
#define QKV_LD 1536
#define SCALE_LOG2E 0.18033688011112042f  /* (1/sqrt(64)) * log2(e), folded into Wq/bq */

__device__ __forceinline__ float b2f(u16 u) {
  union { unsigned u32; float f; } x; x.u32 = ((unsigned)u) << 16; return x.f;
}
__device__ __forceinline__ u16 f2b(float f) {
  union { float f; unsigned u; } x; x.f = f;
  unsigned r = x.u + 0x7FFFu + ((x.u >> 16) & 1u);   // RNE
  return (u16)(r >> 16);
}
// async global->LDS, 16B per lane; LDS dest = wave-uniform base + lane*16 (m97)
__device__ __forceinline__ void gld16(const u16* g, u16* l) {
  __builtin_amdgcn_global_load_lds(
      (const __attribute__((address_space(1))) unsigned int*)g,
      (__attribute__((address_space(3))) unsigned int*)l, 16, 0, 0);
}
// raw workgroup barrier (NO vmcnt/lgkmcnt drain) + compiler memory fences
__device__ __forceinline__ void barrier_raw() {
  asm volatile("" ::: "memory");
  __builtin_amdgcn_s_barrier();
  asm volatile("" ::: "memory");
}
// drain LDS ops only (ds_write visibility) -- leaves global loads in flight
__device__ __forceinline__ void lgkm0() {
  asm volatile("s_waitcnt lgkmcnt(0)" ::: "memory");
}

// ---------- weight transpose + f32->bf16 (scale folds attn score scale into Wq) ----------
__global__ __launch_bounds__(256) void transpose_cvt_kernel(
    const float* __restrict__ src, u16* __restrict__ dst, int K, int N, size_t dstZ,
    float scale)
{
  __shared__ float t[32][33];
  const int z = blockIdx.z;
  src += (size_t)z * K * N;
  dst += (size_t)z * dstZ;
  const int n0 = blockIdx.x * 32, k0 = blockIdx.y * 32;
  const int tx = threadIdx.x, ty = threadIdx.y;  // 32 x 8
#pragma unroll
  for (int i = 0; i < 32; i += 8)
    t[ty + i][tx] = src[(size_t)(k0 + ty + i) * N + n0 + tx];
  __syncthreads();
#pragma unroll
  for (int i = 0; i < 32; i += 8)
    dst[(size_t)(n0 + ty + i) * K + k0 + tx] = f2b(t[tx][ty + i] * scale);
}

// ---------- concat per-layer q/k/v biases into [L][1536]; bq pre-scaled ----------
__global__ __launch_bounds__(256) void concat_bias_kernel(
    const float* __restrict__ bq, const float* __restrict__ bk,
    const float* __restrict__ bv, float* __restrict__ dst)
{
  const int l = blockIdx.x, t = threadIdx.x;
#pragma unroll
  for (int j = t; j < 512; j += 256) {
    dst[l * QKV_LD + j]        = bq[l * 512 + j] * SCALE_LOG2E;
    dst[l * QKV_LD + 512 + j]  = bk[l * 512 + j];
    dst[l * QKV_LD + 1024 + j] = bv[l * 512 + j];
  }
}

// ---------- embedding: h = emb[ids]*sqrt(D) + pe[s] ----------
__global__ __launch_bounds__(256) void embed_kernel(
    const int* __restrict__ ids, const float* __restrict__ emb,
    const float* __restrict__ pe, float* __restrict__ Hf, u16* __restrict__ Hb)
{
  const int row = blockIdx.x;
  const int s = row & (SEQ - 1);
  const int id = ids[row];
  const int tid = threadIdx.x;
#pragma unroll
  for (int u = 0; u < 2; ++u) {
    const int d = tid + u * 256;
    float v = emb[(size_t)id * D_MODEL + d] * 22.62741699796952f + pe[(size_t)s * D_MODEL + d];
    Hf[(size_t)row * D_MODEL + d] = v;
    Hb[(size_t)row * D_MODEL + d] = f2b(v);
  }
}

// ---------- 256x256 phase-split bf16 GEMM (m201-style, plain HIP) ----------
// 8 waves (2M x 4N), BK=64, 128 KB dynamic LDS (2 dbuf x [256][64] x A,B).
template<bool RELU, bool VT>
__global__ __launch_bounds__(512, 2) void gemm256_kernel(
    const u16* __restrict__ A, const u16* __restrict__ Bt,
    const float* __restrict__ bias,
    u16* __restrict__ Cb, u16* __restrict__ Vtp,
    int M, int N, int K)
{
  extern __shared__ __align__(16) u16 smem[];
  u16* Asm = smem;              // [2][256][64] u16 = 64 KB
  u16* Bsm = smem + 32768;      // [2][256][64] u16 = 64 KB
  const int tid = threadIdx.x;
  const int wave = tid >> 6, lane = tid & 63;
  const int lm = lane & 15, quad = lane >> 4, l7 = lm & 7;
  const int wm = wave >> 2, wn = wave & 3;     // 2 x 4 wave grid
  const int bm = blockIdx.x * 256, bn = blockIdx.y * 256;

  const int srow = tid >> 3;
  const int scg = (tid & 7) ^ (srow & 7);      // pre-swizzled source chunk
  const u16* Ap = A  + (size_t)(bm + srow) * K + scg * 8;
  const u16* Bp = Bt + (size_t)(bn + srow) * K + scg * 8;
  u16* uA = Asm + wave * 512;                  // wave-uniform LDS bases
  u16* uB = Bsm + wave * 512;

  f32x4 acc[8][4] = {};

  const int NT = K >> 6;
  auto stage = [&](int buf, int t) {
    const size_t ko = (size_t)t << 6;
#pragma unroll
    for (int p = 0; p < 4; ++p)
      gld16(Ap + (size_t)(p * 64) * K + ko, uA + buf * 16384 + p * 4096);
#pragma unroll
    for (int p = 0; p < 4; ++p)
      gld16(Bp + (size_t)(p * 64) * K + ko, uB + buf * 16384 + p * 4096);
  };

  stage(0, 0);
  __syncthreads();                             // tile 0 resident

  const int sl0 = (quad ^ l7) << 3;            // kh=0 slot (u16 units)
  const int sl1 = ((quad + 4) ^ l7) << 3;      // kh=1 slot

#pragma unroll 1
  for (int t = 0; t < NT; ++t) {
    const int cur = t & 1;
    if (t + 1 < NT) stage(cur ^ 1, t + 1);     // 8 async loads, ~full-tile window
    const u16* as_ = Asm + cur * 16384 + (wm * 128 + lm) * 64;
    const u16* bs_ = Bsm + cur * 16384 + (wn * 64 + lm) * 64;
    bf16x8 af[4][2], b01[2][2], b23[2][2];
    // ---- P0
#pragma unroll
    for (int i = 0; i < 4; ++i) {
      af[i][0] = *(const bf16x8*)&as_[i * 1024 + sl0];
      af[i][1] = *(const bf16x8*)&as_[i * 1024 + sl1];
    }
#pragma unroll
    for (int j = 0; j < 2; ++j) {
      b01[j][0] = *(const bf16x8*)&bs_[j * 1024 + sl0];
      b01[j][1] = *(const bf16x8*)&bs_[j * 1024 + sl1];
    }
    __builtin_amdgcn_s_setprio(1);
#pragma unroll
    for (int i = 0; i < 4; ++i)
#pragma unroll
      for (int j = 0; j < 2; ++j) {
        acc[i][j] = __builtin_amdgcn_mfma_f32_16x16x32_bf16(af[i][0], b01[j][0], acc[i][j], 0, 0, 0);
        acc[i][j] = __builtin_amdgcn_mfma_f32_16x16x32_bf16(af[i][1], b01[j][1], acc[i][j], 0, 0, 0);
      }
    __builtin_amdgcn_s_setprio(0);
    barrier_raw();
    // ---- P1
#pragma unroll
    for (int j = 0; j < 2; ++j) {
      b23[j][0] = *(const bf16x8*)&bs_[(j + 2) * 1024 + sl0];
      b23[j][1] = *(const bf16x8*)&bs_[(j + 2) * 1024 + sl1];
    }
    __builtin_amdgcn_s_setprio(1);
#pragma unroll
    for (int i = 0; i < 4; ++i)
#pragma unroll
      for (int j = 0; j < 2; ++j) {
        acc[i][j + 2] = __builtin_amdgcn_mfma_f32_16x16x32_bf16(af[i][0], b23[j][0], acc[i][j + 2], 0, 0, 0);
        acc[i][j + 2] = __builtin_amdgcn_mfma_f32_16x16x32_bf16(af[i][1], b23[j][1], acc[i][j + 2], 0, 0, 0);
      }
    __builtin_amdgcn_s_setprio(0);
    barrier_raw();
    // ---- P2
#pragma unroll
    for (int i = 0; i < 4; ++i) {
      af[i][0] = *(const bf16x8*)&as_[(i + 4) * 1024 + sl0];
      af[i][1] = *(const bf16x8*)&as_[(i + 4) * 1024 + sl1];
    }
    __builtin_amdgcn_s_setprio(1);
#pragma unroll
    for (int i = 0; i < 4; ++i)
#pragma unroll
      for (int j = 0; j < 2; ++j) {
        acc[i + 4][j + 2] = __builtin_amdgcn_mfma_f32_16x16x32_bf16(af[i][0], b23[j][0], acc[i + 4][j + 2], 0, 0, 0);
        acc[i + 4][j + 2] = __builtin_amdgcn_mfma_f32_16x16x32_bf16(af[i][1], b23[j][1], acc[i + 4][j + 2], 0, 0, 0);
      }
    __builtin_amdgcn_s_setprio(0);
    barrier_raw();
    // ---- P3
#pragma unroll
    for (int j = 0; j < 2; ++j) {
      b01[j][0] = *(const bf16x8*)&bs_[j * 1024 + sl0];
      b01[j][1] = *(const bf16x8*)&bs_[j * 1024 + sl1];
    }
    __builtin_amdgcn_s_setprio(1);
#pragma unroll
    for (int i = 0; i < 4; ++i)
#pragma unroll
      for (int j = 0; j < 2; ++j) {
        acc[i + 4][j] = __builtin_amdgcn_mfma_f32_16x16x32_bf16(af[i][0], b01[j][0], acc[i + 4][j], 0, 0, 0);
        acc[i + 4][j] = __builtin_amdgcn_mfma_f32_16x16x32_bf16(af[i][1], b01[j][1], acc[i + 4][j], 0, 0, 0);
      }
    __builtin_amdgcn_s_setprio(0);
    if (t + 1 < NT) {
      asm volatile("s_waitcnt vmcnt(0)" ::: "memory");
      barrier_raw();
    }
  }

  const int mbase = bm + wm * 128 + quad * 4;
  const int nbase = bn + wn * 64 + lm;
#pragma unroll
  for (int i = 0; i < 8; ++i) {
#pragma unroll
    for (int j = 0; j < 4; ++j) {
      const int n = nbase + j * 16;
      const float bv = bias[n];
      float vv[4];
#pragma unroll
      for (int r = 0; r < 4; ++r) {
        float v = acc[i][j][r] + bv;
        if (RELU) v = fmaxf(v, 0.f);
        vv[r] = v;
      }
      if (VT && n >= 1024) {
        const int hh = (n - 1024) >> 6, d = (n - 1024) & 63;
        const int mm = mbase + i * 16;               // 4-aligned
        const int bb = mm >> 10, ss = mm & 1023;
        us4 pk;
#pragma unroll
        for (int r = 0; r < 4; ++r) pk[r] = f2b(vv[r]);
        *(us4*)&Vtp[(((size_t)(bb * NHEAD + hh)) * 64 + d) * SEQ + ss] = pk;
      } else {
#pragma unroll
        for (int r = 0; r < 4; ++r) {
          const int m = mbase + i * 16 + r;
          Cb[(size_t)m * N + n] = f2b(vv[r]);
        }
      }
    }
  }
}

// ---------- full-row GEMM (N=512) with fused residual+LayerNorm epilogue ----------
// T14 reg-staged pipeline: global->REG loads for tile t+2 issued a full tile
// before their ds_write; compiler's precise vmcnt(N) before the write keeps
// them in flight across barriers (no vmcnt(0) drain anywhere in the loop --
// R3/R5's gld16 structure drained every tile and was pinned at ~46us with
// per-CU ingest 20B/cy). Barriers are lgkmcnt(0)+raw s_barrier only.
// Buffer-reuse safety (2 barriers between last-read and overwrite):
//   write buf1 @half-A(t): last readers = compute(t-1)@half-B(t-2);
//     barriers since: end-of-iter + post-write; ds_reads complete before
//     barrier (MFMA consumption forces lgkm wait).
//   write buf0 @half-B(t): last readers = compute(t)@half-A(t); two
//     barriers in between.
// LDS layout/read addressing identical to R5 (proven 0 conflicts);
// ascending-K order -> numerics bitwise identical.
// BM=64 (FFN2: balances L3 broadcast vs per-CU port) or BM=32 (K=512
// shapes: grid 256 uses all CUs).
template<int BM, bool LN>
__global__ __launch_bounds__(512, 2) void gemm_ln_kernel(
    const u16* __restrict__ A, const u16* __restrict__ Bt,
    const float* __restrict__ bias,
    const float* __restrict__ gw, const float* __restrict__ bw,
    float* __restrict__ Hf, u16* __restrict__ Hb, float* __restrict__ Cf,
    int K)
{
  constexpr int IT = BM / 16;                  // 2 (BM32) or 4 (BM64)
  extern __shared__ __align__(16) u16 smem[];
  u16* Asm = smem;                             // [2][BM][64] u16
  u16* Bsm = smem + 2 * BM * 64;               // [2][512][64] u16 = 128 KB
  float* red = (float*)(smem + 2 * BM * 64 + 65536);
  const int tid = threadIdx.x;
  const int wave = tid >> 6, lane = tid & 63;
  const int lm = lane & 15, quad = lane >> 4, l7 = lm & 7;
  const int bm = blockIdx.x * BM;

  const int srow = tid >> 3;                   // 0..63
  const int scg = (tid & 7) ^ (srow & 7);      // pre-swizzled source chunk
  const bool doA = (BM == 64) || (wave < 4);   // BM=32: waves 0-3 stage A
  const u16* Ap = A  + (size_t)(bm + (doA ? srow : 0)) * K + scg * 8;
  const u16* Bp = Bt + (size_t)srow * K + scg * 8;
  // per-lane LDS write addresses (linear, == gld16 placement)
  u16* wB = Bsm + wave * 512 + (lane << 3);
  u16* wA = Asm + wave * 512 + (lane << 3);

  f32x4 acc[IT][4] = {};
  const int NT = K >> 6;

  uint4v B0[8], B1[8], A0, A1;
  auto loadr = [&](uint4v (&rB)[8], uint4v& rA, int t) {
    const size_t ko = (size_t)t << 6;
#pragma unroll
    for (int p = 0; p < 8; ++p)
      rB[p] = *(const uint4v*)(Bp + (size_t)(p * 64) * K + ko);
    if (doA) rA = *(const uint4v*)(Ap + ko);
  };
  auto writes = [&](uint4v (&rB)[8], uint4v& rA, int buf) {
#pragma unroll
    for (int p = 0; p < 8; ++p)
      *(uint4v*)(wB + buf * 32768 + p * 4096) = rB[p];
    if (doA) *(uint4v*)(wA + buf * (BM * 64)) = rA;
  };
  auto compute = [&](int buf) {
    const u16* as_ = Asm + buf * (BM * 64) + lm * 64;
    const u16* bs_ = Bsm + buf * 32768 + (wave * 64 + lm) * 64;
#pragma unroll
    for (int kh = 0; kh < 2; ++kh) {
      const int slot = ((kh * 4 + quad) ^ l7) << 3;
      bf16x8 af[IT], bg[4];
#pragma unroll
      for (int i = 0; i < IT; ++i)
        af[i] = *(const bf16x8*)&as_[i * 1024 + slot];
#pragma unroll
      for (int j = 0; j < 4; ++j)
        bg[j] = *(const bf16x8*)&bs_[j * 1024 + slot];
#pragma unroll
      for (int i = 0; i < IT; ++i)
#pragma unroll
        for (int j = 0; j < 4; ++j)
          acc[i][j] = __builtin_amdgcn_mfma_f32_16x16x32_bf16(af[i], bg[j], acc[i][j], 0, 0, 0);
    }
  };

  // prologue: tile0 -> buf0; tiles 1,2 in flight in regs
  loadr(B0, A0, 0);
  writes(B0, A0, 0);        // compiler waits the 9 tile-0 loads here
  loadr(B0, A0, 1);
  loadr(B1, A1, 2);         // NT >= 8 always
  lgkm0();
  barrier_raw();            // buf0 visible

#pragma unroll 1
  for (int t = 0; t < NT; t += 2) {
    // -------- half A: tile t from buf0; t+1 in B0; t+2 in B1 --------
    compute(0);
    barrier_raw();
    writes(B0, A0, 1);                    // compiler emits vmcnt(outstanding=B1 set)
    if (t + 3 < NT) loadr(B0, A0, t + 3);
    lgkm0();
    barrier_raw();                        // buf1 visible
    // -------- half B: tile t+1 from buf1; t+2 in B1; t+3 in B0 --------
    compute(1);
    barrier_raw();
    if (t + 2 < NT) {
      writes(B1, A1, 0);
      if (t + 4 < NT) loadr(B1, A1, t + 4);
    }
    lgkm0();
    barrier_raw();                        // buf0 visible
  }

  // ---- epilogue: rows i*16+quad*4+r, cols wave*64+j*16+lm ----
  const int col0 = wave * 64 + lm;
  float bi[4];
#pragma unroll
  for (int j = 0; j < 4; ++j) bi[j] = bias[col0 + j * 16];

  if (LN) {
    float gv[4], bv[4];
#pragma unroll
    for (int j = 0; j < 4; ++j) { gv[j] = gw[col0 + j * 16]; bv[j] = bw[col0 + j * 16]; }
    float x[IT][4][4];
    float ps[IT * 4], pq[IT * 4];
#pragma unroll
    for (int k = 0; k < IT * 4; ++k) { ps[k] = 0.f; pq[k] = 0.f; }
#pragma unroll
    for (int i = 0; i < IT; ++i)
#pragma unroll
      for (int r = 0; r < 4; ++r) {
        const int rowl = i * 16 + quad * 4 + r;
        const size_t rb = (size_t)(bm + rowl) * D_MODEL;
#pragma unroll
        for (int j = 0; j < 4; ++j) {
          float xv = acc[i][j][r] + bi[j] + Hf[rb + col0 + j * 16];
          x[i][j][r] = xv;
          ps[i * 4 + r] += xv;
          pq[i * 4 + r] += xv * xv;
        }
      }
#pragma unroll
    for (int o = 1; o < 16; o <<= 1)
#pragma unroll
      for (int k = 0; k < IT * 4; ++k) {
        ps[k] += __shfl_xor(ps[k], o, 16);
        pq[k] += __shfl_xor(pq[k], o, 16);
      }
    if (lm == 0) {
#pragma unroll
      for (int k = 0; k < IT * 4; ++k) {
        const int rowl = (k >> 2) * 16 + quad * 4 + (k & 3);
        red[wave * BM + rowl] = ps[k];
        red[8 * BM + wave * BM + rowl] = pq[k];
      }
    }
    __syncthreads();
    if (tid < BM) {
      float s = 0.f, q = 0.f;
#pragma unroll
      for (int w = 0; w < 8; ++w) { s += red[w * BM + tid]; q += red[8 * BM + w * BM + tid]; }
      const float mu = s * (1.f / 512.f);
      const float var = q * (1.f / 512.f) - mu * mu;
      red[16 * BM + tid] = mu;
      red[17 * BM + tid] = rsqrtf(var + 1e-5f);
    }
    __syncthreads();
#pragma unroll
    for (int i = 0; i < IT; ++i)
#pragma unroll
      for (int r = 0; r < 4; ++r) {
        const int rowl = i * 16 + quad * 4 + r;
        const float mu = red[16 * BM + rowl];
        const float rs = red[17 * BM + rowl];
        const size_t rb = (size_t)(bm + rowl) * D_MODEL;
#pragma unroll
        for (int j = 0; j < 4; ++j) {
          const float y = (x[i][j][r] - mu) * rs * gv[j] + bv[j];
          Hf[rb + col0 + j * 16] = y;
          Hb[rb + col0 + j * 16] = f2b(y);
        }
      }
  } else {
#pragma unroll
    for (int i = 0; i < IT; ++i)
#pragma unroll
      for (int r = 0; r < 4; ++r) {
        const int rowl = i * 16 + quad * 4 + r;
        const size_t rb = (size_t)(bm + rowl) * D_MODEL;
#pragma unroll
        for (int j = 0; j < 4; ++j)
          Cf[rb + col0 + j * 16] = acc[i][j][r] + bi[j];
      }
  }
}

// ---------- MFMA flash attention + fused row-1023 vmean fixup ----------
__global__ __launch_bounds__(256) void attn_mfma_kernel(
    const u16* __restrict__ QKV, const u16* __restrict__ Vt, u16* __restrict__ O)
{
  __shared__ __align__(16) u16 Ks[64 * 64];
  __shared__ __align__(16) u16 Vs[64 * 64];
  __shared__ __align__(16) u16 Ps[4 * 16 * 64];
  const int tid = threadIdx.x;
  const int wave = tid >> 6, lane = tid & 63;
  const int quad = lane >> 4, l15 = lane & 15;
  const int l7 = l15 & 7;
  const int id = blockIdx.x;
  const int bh = id & 63;                           // id%8 == h -> XCD affinity
  const int b = bh >> 3, h = bh & 7;
  const int g = id >> 6;                            // 0..15 == jt0 (block-uniform)
  const int u = g * 4 + wave;                       // q-unit 0..63
  u16* psw = Ps + wave * (16 * 64);
  const size_t qoff = (size_t)b * SEQ * QKV_LD + h * 64;
  const size_t vtb  = (size_t)bh * 64 * SEQ;

  const int sr = tid >> 3, sc = tid & 7;
  const u16* kg0 = QKV + qoff + 512 + (size_t)sr * QKV_LD + sc * 8;
  const u16* kg1 = kg0 + (size_t)32 * QKV_LD;
  const u16* vg0 = Vt + vtb + (size_t)sr * SEQ + sc * 8;
  const u16* vg1 = vg0 + (size_t)32 * SEQ;
  const int sw = (sc ^ (sr & 7)) << 3;              // (sr+32)&7 == sr&7
  u16* ks0 = &Ks[sr * 64 + sw];
  u16* ks1 = &Ks[(sr + 32) * 64 + sw];
  u16* vs0 = &Vs[sr * 64 + sw];
  u16* vs1 = &Vs[(sr + 32) * 64 + sw];

  const u16* qp = QKV + qoff + (size_t)(u * 16 + l15) * QKV_LD + quad * 8;
  const bf16x8 qf0 = *(const bf16x8*)(qp);
  const bf16x8 qf1 = *(const bf16x8*)(qp + 32);

  f32x4 oacc[4] = {};
  float lsum[4] = {0.f, 0.f, 0.f, 0.f};

  uint4v kr0 = *(const uint4v*)(kg0 + (size_t)(g * 64) * QKV_LD);
  uint4v kr1 = *(const uint4v*)(kg1 + (size_t)(g * 64) * QKV_LD);
  uint4v vr0 = *(const uint4v*)(vg0 + g * 64);
  uint4v vr1 = *(const uint4v*)(vg1 + g * 64);

#pragma unroll 1
  for (int jt = g; jt < 16; ++jt) {
    __syncthreads();
    *(uint4v*)ks0 = kr0; *(uint4v*)ks1 = kr1;
    *(uint4v*)vs0 = vr0; *(uint4v*)vs1 = vr1;
    __syncthreads();
    if (jt < 15) {
      kr0 = *(const uint4v*)(kg0 + (size_t)((jt + 1) * 64) * QKV_LD);
      kr1 = *(const uint4v*)(kg1 + (size_t)((jt + 1) * 64) * QKV_LD);
      vr0 = *(const uint4v*)(vg0 + (jt + 1) * 64);
      vr1 = *(const uint4v*)(vg1 + (jt + 1) * 64);
    }
    f32x4 sacc[4] = {};
#pragma unroll
    for (int nt = 0; nt < 4; ++nt) {
      const int key = nt * 16 + l15, k7 = key & 7;
      bf16x8 kb0 = *(const bf16x8*)&Ks[key * 64 + ((quad ^ k7) << 3)];
      bf16x8 kb1 = *(const bf16x8*)&Ks[key * 64 + (((quad + 4) ^ k7) << 3)];
      sacc[nt] = __builtin_amdgcn_mfma_f32_16x16x32_bf16(qf0, kb0, sacc[nt], 0, 0, 0);
      sacc[nt] = __builtin_amdgcn_mfma_f32_16x16x32_bf16(qf1, kb1, sacc[nt], 0, 0, 0);
    }
    const bool diag = (jt == g);
#pragma unroll
    for (int nt = 0; nt < 4; ++nt)
#pragma unroll
      for (int r = 0; r < 4; ++r) {
        float pv = __builtin_amdgcn_exp2f(sacc[nt][r]);
        if (diag) {
          const int i = u * 16 + quad * 4 + r;
          const int j = jt * 64 + nt * 16 + l15;
          pv = (j > i) ? pv : 0.f;                  // keep strictly j > i
        }
        lsum[r] += pv;
        const int qr = quad * 4 + r;
        const int j2 = nt * 16 + l15;
        psw[qr * 64 + (((j2 >> 3) ^ (qr & 7)) << 3) + (j2 & 7)] = f2b(pv);
      }
    bf16x8 pf0 = *(const bf16x8*)&psw[l15 * 64 + (((quad + 0) ^ l7) << 3)];
    bf16x8 pf1 = *(const bf16x8*)&psw[l15 * 64 + (((quad + 4) ^ l7) << 3)];
#pragma unroll
    for (int nt = 0; nt < 4; ++nt) {
      const int d = nt * 16 + l15, d7 = d & 7;
      bf16x8 vb0 = *(const bf16x8*)&Vs[d * 64 + ((quad ^ d7) << 3)];
      bf16x8 vb1 = *(const bf16x8*)&Vs[d * 64 + (((quad + 4) ^ d7) << 3)];
      oacc[nt] = __builtin_amdgcn_mfma_f32_16x16x32_bf16(pf0, vb0, oacc[nt], 0, 0, 0);
      oacc[nt] = __builtin_amdgcn_mfma_f32_16x16x32_bf16(pf1, vb1, oacc[nt], 0, 0, 0);
    }
  }

#pragma unroll
  for (int o = 1; o < 16; o <<= 1)
#pragma unroll
    for (int r = 0; r < 4; ++r) lsum[r] += __shfl_xor(lsum[r], o, 16);
  float rl[4];
#pragma unroll
  for (int r = 0; r < 4; ++r) rl[r] = 1.0f / lsum[r];
#pragma unroll
  for (int nt = 0; nt < 4; ++nt)
#pragma unroll
    for (int r = 0; r < 4; ++r) {
      const int row = u * 16 + quad * 4 + r;
      O[(size_t)(b * SEQ + row) * D_MODEL + h * DKH + nt * 16 + l15] = f2b(oacc[nt][r] * rl[r]);
    }

  // fused vmean: overwrite row S-1 with uniform mean over all keys
  if (g == 15) {
    __syncthreads();   // order after this block's own row-1023 epilogue store
    const int d = tid >> 2, scv = (tid & 3) * 256;
    const u16* pv = Vt + vtb + (size_t)d * SEQ + scv;
    float s = 0.f;
#pragma unroll 8
    for (int i2 = 0; i2 < 256; ++i2) s += b2f(pv[i2]);
    s += __shfl_xor(s, 1, 64);
    s += __shfl_xor(s, 2, 64);
    if ((tid & 3) == 0)
      O[((size_t)b * SEQ + SEQ - 1) * D_MODEL + h * 64 + d] = f2b(s * (1.f / SEQ));
  }
}

extern "C" void kernel_launch(void* const* d_in, const int* in_sizes, int n_in,
                              void* d_out, int out_size, void* d_ws, size_t ws_size,
                              hipStream_t stream) {
  (void)in_sizes; (void)n_in; (void)out_size; (void)ws_size;
  const int*   ids  = (const int*)  d_in[0];
  const float* emb  = (const float*)d_in[1];
  const float* pe   = (const float*)d_in[2];
  const float* Wq   = (const float*)d_in[3];
  const float* bq   = (const float*)d_in[4];
  const float* Wk   = (const float*)d_in[5];
  const float* bk   = (const float*)d_in[6];
  const float* Wv   = (const float*)d_in[7];
  const float* bv   = (const float*)d_in[8];
  const float* Wo   = (const float*)d_in[9];
  const float* bo   = (const float*)d_in[10];
  const float* g1   = (const float*)d_in[11];
  const float* be1  = (const float*)d_in[12];
  const float* W1   = (const float*)d_in[13];
  const float* b1   = (const float*)d_in[14];
  const float* W2   = (const float*)d_in[15];
  const float* b2   = (const float*)d_in[16];
  const float* g2   = (const float*)d_in[17];
  const float* be2  = (const float*)d_in[18];
  const float* Wout = (const float*)d_in[19];
  const float* bout = (const float*)d_in[20];
  float* out = (float*)d_out;

  static int attr_set = 0;
  if (!attr_set) {
    hipFuncSetAttribute(reinterpret_cast<const void*>(&gemm256_kernel<false, true>),
                        hipFuncAttributeMaxDynamicSharedMemorySize, 131072);
    hipFuncSetAttribute(reinterpret_cast<const void*>(&gemm256_kernel<true, false>),
                        hipFuncAttributeMaxDynamicSharedMemorySize, 131072);
    hipFuncSetAttribute(reinterpret_cast<const void*>(&gemm_ln_kernel<64, true>),
                        hipFuncAttributeMaxDynamicSharedMemorySize, 152064);
    hipFuncSetAttribute(reinterpret_cast<const void*>(&gemm_ln_kernel<32, true>),
                        hipFuncAttributeMaxDynamicSharedMemorySize, 141568);
    hipFuncSetAttribute(reinterpret_cast<const void*>(&gemm_ln_kernel<32, false>),
                        hipFuncAttributeMaxDynamicSharedMemorySize, 141568);
    attr_set = 1;
  }

  char* wsp = (char*)d_ws;
  auto alloc = [&](size_t bytes) -> char* {
    char* p = wsp; wsp += (bytes + 255) & ~(size_t)255; return p;
  };
  const size_t dd  = (size_t)D_MODEL * D_MODEL;      // 262144
  const size_t df  = (size_t)D_MODEL * FFN;          // 1048576
  const size_t dq  = (size_t)QKV_LD * D_MODEL;       // 786432
  u16* wqkv_t = (u16*)alloc(NLAYER * dq * 2);
  u16* wo_t   = (u16*)alloc(NLAYER * dd * 2);
  u16* w1_t   = (u16*)alloc(NLAYER * df * 2);
  u16* w2_t   = (u16*)alloc(NLAYER * df * 2);
  u16* wout_t = (u16*)alloc(dd * 2);
  float* bqkv = (float*)alloc(NLAYER * QKV_LD * 4);
  float* hf   = (float*)alloc((size_t)MROWS * D_MODEL * 4);
  u16*   hb   = (u16*)  alloc((size_t)MROWS * D_MODEL * 2);
  u16*   qkvb = (u16*)  alloc((size_t)MROWS * QKV_LD * 2);   // 24 MB
  u16*   ob   = (u16*)  alloc((size_t)MROWS * D_MODEL * 2);  // 8 MB
  u16*   vt   = (u16*)  alloc((size_t)BATCH * NHEAD * DKH * SEQ * 2);
  u16*   mid  = qkvb;  // FFN mid [8192,2048] aliases qkvb+ob (dead by FFN1; stream-ordered)

  dim3 tb8(32, 8);
  transpose_cvt_kernel<<<dim3(16, 16, NLAYER), tb8, 0, stream>>>(Wq, wqkv_t,            512, 512,  dq, SCALE_LOG2E);
  transpose_cvt_kernel<<<dim3(16, 16, NLAYER), tb8, 0, stream>>>(Wk, wqkv_t + 512*512,  512, 512,  dq, 1.f);
  transpose_cvt_kernel<<<dim3(16, 16, NLAYER), tb8, 0, stream>>>(Wv, wqkv_t + 1024*512, 512, 512,  dq, 1.f);
  transpose_cvt_kernel<<<dim3(16, 16, NLAYER), tb8, 0, stream>>>(Wo, wo_t,   512, 512,  dd, 1.f);
  transpose_cvt_kernel<<<dim3(64, 16, NLAYER), tb8, 0, stream>>>(W1, w1_t,   512, 2048, df, 1.f);
  transpose_cvt_kernel<<<dim3(16, 64, NLAYER), tb8, 0, stream>>>(W2, w2_t,   2048, 512, df, 1.f);
  transpose_cvt_kernel<<<dim3(16, 16, 1),      tb8, 0, stream>>>(Wout, wout_t, 512, 512, dd, 1.f);
  concat_bias_kernel<<<NLAYER, 256, 0, stream>>>(bq, bk, bv, bqkv);

  embed_kernel<<<MROWS, 256, 0, stream>>>(ids, emb, pe, hf, hb);

  for (int l = 0; l < NLAYER; ++l) {
    gemm256_kernel<false, true><<<dim3(32, 6), 512, 131072, stream>>>(
        hb, wqkv_t + l * dq, bqkv + l * QKV_LD, qkvb, vt, MROWS, QKV_LD, 512);
    attn_mfma_kernel<<<1024, 256, 0, stream>>>(qkvb, vt, ob);
    gemm_ln_kernel<32, true><<<256, 512, 141568, stream>>>(
        ob, wo_t + l * dd, bo + l * 512, g1 + l * 512, be1 + l * 512,
        hf, hb, nullptr, 512);
    gemm256_kernel<true, false><<<dim3(32, 8), 512, 131072, stream>>>(
        hb, w1_t + l * df, b1 + l * 2048, mid, nullptr, MROWS, 2048, 512);
    gemm_ln_kernel<64, true><<<128, 512, 152064, stream>>>(
        mid, w2_t + l * df, b2 + l * 512, g2 + l * 512, be2 + l * 512,
        hf, hb, nullptr, 2048);
  }
  gemm_ln_kernel<32, false><<<256, 512, 141568, stream>>>(
      hb, wout_t, bout, nullptr, nullptr, nullptr, nullptr, out, 512);
}

// Round 7
// 969.237 us; speedup vs baseline: 1.0681x; 1.0681x over previous
//
#include <hip/hip_runtime.h>

typedef unsigned short u16;
typedef __attribute__((ext_vector_type(8))) short bf16x8;   // 8 bf16 (4 VGPRs)
typedef __attribute__((ext_vector_type(4))) float f32x4;
typedef __attribute__((ext_vector_type(4))) unsigned int uint4v;
typedef __attribute__((ext_vector_type(4))) unsigned short us4;

#define NLAYER 6
#define D_MODEL 512
#define NHEAD 8
#define DKH 64
#define SEQ 1024
#define BATCH 8
#define FFN 2048
#define MROWS (BATCH * SEQ)  /* 8192 */
#define QKV_LD 1536
#define SCALE_LOG2E 0.18033688011112042f  /* (1/sqrt(64)) * log2(e), folded into Wq/bq */

__device__ __forceinline__ float b2f(u16 u) {
  union { unsigned u32; float f; } x; x.u32 = ((unsigned)u) << 16; return x.f;
}
__device__ __forceinline__ u16 f2b(float f) {
  union { float f; unsigned u; } x; x.f = f;
  unsigned r = x.u + 0x7FFFu + ((x.u >> 16) & 1u);   // RNE
  return (u16)(r >> 16);
}
// async global->LDS, 16B per lane; LDS dest = wave-uniform base + lane*16 (m97)
__device__ __forceinline__ void gld16(const u16* g, u16* l) {
  __builtin_amdgcn_global_load_lds(
      (const __attribute__((address_space(1))) unsigned int*)g,
      (__attribute__((address_space(3))) unsigned int*)l, 16, 0, 0);
}
// raw workgroup barrier (NO vmcnt/lgkmcnt drain) + compiler memory fences
__device__ __forceinline__ void barrier_raw() {
  asm volatile("" ::: "memory");
  __builtin_amdgcn_s_barrier();
  asm volatile("" ::: "memory");
}

// ---------- weight transpose + f32->bf16 (scale folds attn score scale into Wq) ----------
__global__ __launch_bounds__(256) void transpose_cvt_kernel(
    const float* __restrict__ src, u16* __restrict__ dst, int K, int N, size_t dstZ,
    float scale)
{
  __shared__ float t[32][33];
  const int z = blockIdx.z;
  src += (size_t)z * K * N;
  dst += (size_t)z * dstZ;
  const int n0 = blockIdx.x * 32, k0 = blockIdx.y * 32;
  const int tx = threadIdx.x, ty = threadIdx.y;  // 32 x 8
#pragma unroll
  for (int i = 0; i < 32; i += 8)
    t[ty + i][tx] = src[(size_t)(k0 + ty + i) * N + n0 + tx];
  __syncthreads();
#pragma unroll
  for (int i = 0; i < 32; i += 8)
    dst[(size_t)(n0 + ty + i) * K + k0 + tx] = f2b(t[tx][ty + i] * scale);
}

// ---------- concat per-layer q/k/v biases into [L][1536]; bq pre-scaled ----------
__global__ __launch_bounds__(256) void concat_bias_kernel(
    const float* __restrict__ bq, const float* __restrict__ bk,
    const float* __restrict__ bv, float* __restrict__ dst)
{
  const int l = blockIdx.x, t = threadIdx.x;
#pragma unroll
  for (int j = t; j < 512; j += 256) {
    dst[l * QKV_LD + j]        = bq[l * 512 + j] * SCALE_LOG2E;
    dst[l * QKV_LD + 512 + j]  = bk[l * 512 + j];
    dst[l * QKV_LD + 1024 + j] = bv[l * 512 + j];
  }
}

// ---------- embedding: h = emb[ids]*sqrt(D) + pe[s] ----------
__global__ __launch_bounds__(256) void embed_kernel(
    const int* __restrict__ ids, const float* __restrict__ emb,
    const float* __restrict__ pe, float* __restrict__ Hf, u16* __restrict__ Hb)
{
  const int row = blockIdx.x;
  const int s = row & (SEQ - 1);
  const int id = ids[row];
  const int tid = threadIdx.x;
#pragma unroll
  for (int u = 0; u < 2; ++u) {
    const int d = tid + u * 256;
    float v = emb[(size_t)id * D_MODEL + d] * 22.62741699796952f + pe[(size_t)s * D_MODEL + d];
    Hf[(size_t)row * D_MODEL + d] = v;
    Hb[(size_t)row * D_MODEL + d] = f2b(v);
  }
}

// ---------- 2-phase bf16 MFMA GEMM (N-split, high occupancy): C = A @ Bt^T + bias ----------
// BMTx128 tile, BK=64, 2-buf gld16 staging. 48 KB LDS -> 3 blocks/CU, 12
// waves/CU: TLP hides the staging latency that the 1-block/CU full-row
// kernel could never hide (R3-R6 lesson). Used for FFN2 (grid 128x4).
template<int BMT, bool RELU, bool OUTF, bool OUTB, bool VT>
__global__ __launch_bounds__(256) void gemm_kernel(
    const u16* __restrict__ A, const u16* __restrict__ Bt,
    const float* __restrict__ bias,
    float* __restrict__ Cf, u16* __restrict__ Cb, u16* __restrict__ Vtp,
    int M, int N, int K)
{
  constexpr int IT = BMT / 32;                 // 2 (BMT=64)
  constexpr int AHALF = BMT * 64;              // u16 per A buffer
  constexpr int BHALF = 128 * 64;              // u16 per B buffer
  __shared__ __align__(16) u16 As[2 * AHALF];
  __shared__ __align__(16) u16 Bs[2 * BHALF];
  const int tid = threadIdx.x;
  const int bm = blockIdx.x * BMT, bn = blockIdx.y * 128;
  const int wave = tid >> 6, lane = tid & 63;
  const int lm = lane & 15, quad = lane >> 4;
  const int wm = (wave & 1) * (BMT / 2), wn = (wave >> 1) * 64;

  const int sr = tid >> 3;                     // 0..31
  const int sc = (tid & 7) ^ (sr & 7);         // pre-swizzled source chunk
  const u16* Ap = A  + (size_t)(bm + sr) * K + sc * 8;
  const u16* Bp = Bt + (size_t)(bn + sr) * K + sc * 8;
  u16* lA = As + wave * 512;
  u16* lB = Bs + wave * 512;

  f32x4 acc[IT][4] = {};

  const int nt = K >> 6;
  auto stage = [&](int buf, int t) {
    const size_t ko = (size_t)t << 6;
#pragma unroll
    for (int p = 0; p < BMT / 32; ++p)
      gld16(Ap + (size_t)(p * 32) * K + ko, lA + buf * AHALF + p * 2048);
#pragma unroll
    for (int p = 0; p < 4; ++p)
      gld16(Bp + (size_t)(p * 32) * K + ko, lB + buf * BHALF + p * 2048);
  };

  stage(0, 0);
  __syncthreads();

  for (int t = 0; t < nt; ++t) {
    const int cur = t & 1;
    if (t + 1 < nt) stage(cur ^ 1, t + 1);
    const u16* as = As + cur * AHALF;
    const u16* bs = Bs + cur * BHALF;
#pragma unroll
    for (int kh = 0; kh < 2; ++kh) {
      bf16x8 af[IT], bg[4];
#pragma unroll
      for (int i = 0; i < IT; ++i) {
        const int row = wm + i * 16 + lm;
        af[i] = *(const bf16x8*)&as[row * 64 + (((kh * 4 + quad) ^ (row & 7)) << 3)];
      }
#pragma unroll
      for (int j = 0; j < 4; ++j) {
        const int row = wn + j * 16 + lm;
        bg[j] = *(const bf16x8*)&bs[row * 64 + (((kh * 4 + quad) ^ (row & 7)) << 3)];
      }
#pragma unroll
      for (int i = 0; i < IT; ++i)
#pragma unroll
        for (int j = 0; j < 4; ++j)
          acc[i][j] = __builtin_amdgcn_mfma_f32_16x16x32_bf16(af[i], bg[j], acc[i][j], 0, 0, 0);
    }
    __syncthreads();
  }

  const int mbase = bm + wm + quad * 4;
  const int nbase = bn + wn + lm;
#pragma unroll
  for (int i = 0; i < IT; ++i) {
#pragma unroll
    for (int j = 0; j < 4; ++j) {
      const int n = nbase + j * 16;
      const float bv = bias[n];
      float vv[4];
#pragma unroll
      for (int r = 0; r < 4; ++r) {
        float v = acc[i][j][r] + bv;
        if (RELU) v = fmaxf(v, 0.f);
        vv[r] = v;
      }
      if (VT && n >= 1024) {
        const int hh = (n - 1024) >> 6, d = (n - 1024) & 63;
        const int mm = mbase + i * 16;
        const int bb = mm >> 10, ss = mm & 1023;
        us4 pk;
#pragma unroll
        for (int r = 0; r < 4; ++r) pk[r] = f2b(vv[r]);
        *(us4*)&Vtp[(((size_t)(bb * NHEAD + hh)) * 64 + d) * SEQ + ss] = pk;
      } else {
#pragma unroll
        for (int r = 0; r < 4; ++r) {
          const int m = mbase + i * 16 + r;
          if (OUTF) Cf[(size_t)m * N + n] = vv[r];
          if (OUTB) Cb[(size_t)m * N + n] = f2b(vv[r]);
        }
      }
    }
  }
}

// ---------- 256x256 phase-split bf16 GEMM (m201-style, plain HIP) ----------
// 8 waves (2M x 4N), BK=64, 128 KB dynamic LDS (2 dbuf x [256][64] x A,B).
template<bool RELU, bool VT>
__global__ __launch_bounds__(512, 2) void gemm256_kernel(
    const u16* __restrict__ A, const u16* __restrict__ Bt,
    const float* __restrict__ bias,
    u16* __restrict__ Cb, u16* __restrict__ Vtp,
    int M, int N, int K)
{
  extern __shared__ __align__(16) u16 smem[];
  u16* Asm = smem;              // [2][256][64] u16 = 64 KB
  u16* Bsm = smem + 32768;      // [2][256][64] u16 = 64 KB
  const int tid = threadIdx.x;
  const int wave = tid >> 6, lane = tid & 63;
  const int lm = lane & 15, quad = lane >> 4, l7 = lm & 7;
  const int wm = wave >> 2, wn = wave & 3;     // 2 x 4 wave grid
  const int bm = blockIdx.x * 256, bn = blockIdx.y * 256;

  const int srow = tid >> 3;
  const int scg = (tid & 7) ^ (srow & 7);      // pre-swizzled source chunk
  const u16* Ap = A  + (size_t)(bm + srow) * K + scg * 8;
  const u16* Bp = Bt + (size_t)(bn + srow) * K + scg * 8;
  u16* uA = Asm + wave * 512;                  // wave-uniform LDS bases
  u16* uB = Bsm + wave * 512;

  f32x4 acc[8][4] = {};

  const int NT = K >> 6;
  auto stage = [&](int buf, int t) {
    const size_t ko = (size_t)t << 6;
#pragma unroll
    for (int p = 0; p < 4; ++p)
      gld16(Ap + (size_t)(p * 64) * K + ko, uA + buf * 16384 + p * 4096);
#pragma unroll
    for (int p = 0; p < 4; ++p)
      gld16(Bp + (size_t)(p * 64) * K + ko, uB + buf * 16384 + p * 4096);
  };

  stage(0, 0);
  __syncthreads();                             // tile 0 resident

  const int sl0 = (quad ^ l7) << 3;            // kh=0 slot (u16 units)
  const int sl1 = ((quad + 4) ^ l7) << 3;      // kh=1 slot

#pragma unroll 1
  for (int t = 0; t < NT; ++t) {
    const int cur = t & 1;
    if (t + 1 < NT) stage(cur ^ 1, t + 1);     // 8 async loads, ~full-tile window
    const u16* as_ = Asm + cur * 16384 + (wm * 128 + lm) * 64;
    const u16* bs_ = Bsm + cur * 16384 + (wn * 64 + lm) * 64;
    bf16x8 af[4][2], b01[2][2], b23[2][2];
    // ---- P0
#pragma unroll
    for (int i = 0; i < 4; ++i) {
      af[i][0] = *(const bf16x8*)&as_[i * 1024 + sl0];
      af[i][1] = *(const bf16x8*)&as_[i * 1024 + sl1];
    }
#pragma unroll
    for (int j = 0; j < 2; ++j) {
      b01[j][0] = *(const bf16x8*)&bs_[j * 1024 + sl0];
      b01[j][1] = *(const bf16x8*)&bs_[j * 1024 + sl1];
    }
    __builtin_amdgcn_s_setprio(1);
#pragma unroll
    for (int i = 0; i < 4; ++i)
#pragma unroll
      for (int j = 0; j < 2; ++j) {
        acc[i][j] = __builtin_amdgcn_mfma_f32_16x16x32_bf16(af[i][0], b01[j][0], acc[i][j], 0, 0, 0);
        acc[i][j] = __builtin_amdgcn_mfma_f32_16x16x32_bf16(af[i][1], b01[j][1], acc[i][j], 0, 0, 0);
      }
    __builtin_amdgcn_s_setprio(0);
    barrier_raw();
    // ---- P1
#pragma unroll
    for (int j = 0; j < 2; ++j) {
      b23[j][0] = *(const bf16x8*)&bs_[(j + 2) * 1024 + sl0];
      b23[j][1] = *(const bf16x8*)&bs_[(j + 2) * 1024 + sl1];
    }
    __builtin_amdgcn_s_setprio(1);
#pragma unroll
    for (int i = 0; i < 4; ++i)
#pragma unroll
      for (int j = 0; j < 2; ++j) {
        acc[i][j + 2] = __builtin_amdgcn_mfma_f32_16x16x32_bf16(af[i][0], b23[j][0], acc[i][j + 2], 0, 0, 0);
        acc[i][j + 2] = __builtin_amdgcn_mfma_f32_16x16x32_bf16(af[i][1], b23[j][1], acc[i][j + 2], 0, 0, 0);
      }
    __builtin_amdgcn_s_setprio(0);
    barrier_raw();
    // ---- P2
#pragma unroll
    for (int i = 0; i < 4; ++i) {
      af[i][0] = *(const bf16x8*)&as_[(i + 4) * 1024 + sl0];
      af[i][1] = *(const bf16x8*)&as_[(i + 4) * 1024 + sl1];
    }
    __builtin_amdgcn_s_setprio(1);
#pragma unroll
    for (int i = 0; i < 4; ++i)
#pragma unroll
      for (int j = 0; j < 2; ++j) {
        acc[i + 4][j + 2] = __builtin_amdgcn_mfma_f32_16x16x32_bf16(af[i][0], b23[j][0], acc[i + 4][j + 2], 0, 0, 0);
        acc[i + 4][j + 2] = __builtin_amdgcn_mfma_f32_16x16x32_bf16(af[i][1], b23[j][1], acc[i + 4][j + 2], 0, 0, 0);
      }
    __builtin_amdgcn_s_setprio(0);
    barrier_raw();
    // ---- P3
#pragma unroll
    for (int j = 0; j < 2; ++j) {
      b01[j][0] = *(const bf16x8*)&bs_[j * 1024 + sl0];
      b01[j][1] = *(const bf16x8*)&bs_[j * 1024 + sl1];
    }
    __builtin_amdgcn_s_setprio(1);
#pragma unroll
    for (int i = 0; i < 4; ++i)
#pragma unroll
      for (int j = 0; j < 2; ++j) {
        acc[i + 4][j] = __builtin_amdgcn_mfma_f32_16x16x32_bf16(af[i][0], b01[j][0], acc[i + 4][j], 0, 0, 0);
        acc[i + 4][j] = __builtin_amdgcn_mfma_f32_16x16x32_bf16(af[i][1], b01[j][1], acc[i + 4][j], 0, 0, 0);
      }
    __builtin_amdgcn_s_setprio(0);
    if (t + 1 < NT) {
      asm volatile("s_waitcnt vmcnt(0)" ::: "memory");
      barrier_raw();
    }
  }

  const int mbase = bm + wm * 128 + quad * 4;
  const int nbase = bn + wn * 64 + lm;
#pragma unroll
  for (int i = 0; i < 8; ++i) {
#pragma unroll
    for (int j = 0; j < 4; ++j) {
      const int n = nbase + j * 16;
      const float bv = bias[n];
      float vv[4];
#pragma unroll
      for (int r = 0; r < 4; ++r) {
        float v = acc[i][j][r] + bv;
        if (RELU) v = fmaxf(v, 0.f);
        vv[r] = v;
      }
      if (VT && n >= 1024) {
        const int hh = (n - 1024) >> 6, d = (n - 1024) & 63;
        const int mm = mbase + i * 16;               // 4-aligned
        const int bb = mm >> 10, ss = mm & 1023;
        us4 pk;
#pragma unroll
        for (int r = 0; r < 4; ++r) pk[r] = f2b(vv[r]);
        *(us4*)&Vtp[(((size_t)(bb * NHEAD + hh)) * 64 + d) * SEQ + ss] = pk;
      } else {
#pragma unroll
        for (int r = 0; r < 4; ++r) {
          const int m = mbase + i * 16 + r;
          Cb[(size_t)m * N + n] = f2b(vv[r]);
        }
      }
    }
  }
}

// ---------- full-row GEMM (N=512, K=512) with fused residual+LayerNorm epilogue ----------
// R3-exact BM=32 kernel (991us config). Only used where K=512 (Wo, Wout):
// NT=8 tiles keeps the full-row broadcast cheap enough to beat GEMM+add_ln.
template<bool LN>
__global__ __launch_bounds__(512, 2) void gemm_ln_kernel(
    const u16* __restrict__ A, const u16* __restrict__ Bt,
    const float* __restrict__ bias,
    const float* __restrict__ gw, const float* __restrict__ bw,
    float* __restrict__ Hf, u16* __restrict__ Hb, float* __restrict__ Cf,
    int K)
{
  extern __shared__ __align__(16) u16 smem[];
  u16* Asm = smem;
  u16* Bsm = smem + 4096;
  float* red = (float*)(smem + 69632);  // sred[256] qred[256] mu[32] rs[32]
  const int tid = threadIdx.x;
  const int wave = tid >> 6, lane = tid & 63;
  const int lm = lane & 15, quad = lane >> 4, l7 = lm & 7;
  const int bm = blockIdx.x * 32;

  const int srow = tid >> 3;                   // 0..63
  const int scg = (tid & 7) ^ (srow & 7);      // pre-swizzled source chunk
  const u16* Ap = A  + (size_t)(bm + srow) * K + scg * 8;  // used rows <32
  const u16* Bp = Bt + (size_t)srow * K + scg * 8;
  u16* uA = Asm + wave * 512;                  // waves 0..3 stage A
  u16* uB = Bsm + wave * 512;

  f32x4 acc[2][4] = {};
  const int NT = K >> 6;
  auto stage = [&](int buf, int t) {
    const size_t ko = (size_t)t << 6;
    if (wave < 4) gld16(Ap + ko, uA + buf * 2048);
#pragma unroll
    for (int p = 0; p < 8; ++p)
      gld16(Bp + (size_t)(p * 64) * K + ko, uB + buf * 32768 + p * 4096);
  };

  stage(0, 0);
  __syncthreads();

#pragma unroll 1
  for (int t = 0; t < NT; ++t) {
    const int cur = t & 1;
    if (t + 1 < NT) stage(cur ^ 1, t + 1);
    const u16* as_ = Asm + cur * 2048 + lm * 64;
    const u16* bs_ = Bsm + cur * 32768 + (wave * 64 + lm) * 64;
#pragma unroll
    for (int kh = 0; kh < 2; ++kh) {
      const int slot = ((kh * 4 + quad) ^ l7) << 3;
      bf16x8 af[2], bg[4];
      af[0] = *(const bf16x8*)&as_[slot];
      af[1] = *(const bf16x8*)&as_[1024 + slot];
#pragma unroll
      for (int j = 0; j < 4; ++j)
        bg[j] = *(const bf16x8*)&bs_[j * 1024 + slot];
#pragma unroll
      for (int i = 0; i < 2; ++i)
#pragma unroll
        for (int j = 0; j < 4; ++j)
          acc[i][j] = __builtin_amdgcn_mfma_f32_16x16x32_bf16(af[i], bg[j], acc[i][j], 0, 0, 0);
    }
    __syncthreads();
  }

  // ---- epilogue: rows i*16+quad*4+r (8/thread), cols wave*64+j*16+lm ----
  const int col0 = wave * 64 + lm;
  float bi[4];
#pragma unroll
  for (int j = 0; j < 4; ++j) bi[j] = bias[col0 + j * 16];

  if (LN) {
    float gv[4], bv[4];
#pragma unroll
    for (int j = 0; j < 4; ++j) { gv[j] = gw[col0 + j * 16]; bv[j] = bw[col0 + j * 16]; }
    float x[2][4][4];
    float ps[8], pq[8];
#pragma unroll
    for (int k = 0; k < 8; ++k) { ps[k] = 0.f; pq[k] = 0.f; }
#pragma unroll
    for (int i = 0; i < 2; ++i)
#pragma unroll
      for (int r = 0; r < 4; ++r) {
        const int rowl = i * 16 + quad * 4 + r;
        const size_t rb = (size_t)(bm + rowl) * D_MODEL;
#pragma unroll
        for (int j = 0; j < 4; ++j) {
          float xv = acc[i][j][r] + bi[j] + Hf[rb + col0 + j * 16];
          x[i][j][r] = xv;
          ps[i * 4 + r] += xv;
          pq[i * 4 + r] += xv * xv;
        }
      }
#pragma unroll
    for (int o = 1; o < 16; o <<= 1)
#pragma unroll
      for (int k = 0; k < 8; ++k) {
        ps[k] += __shfl_xor(ps[k], o, 16);
        pq[k] += __shfl_xor(pq[k], o, 16);
      }
    if (lm == 0) {
#pragma unroll
      for (int k = 0; k < 8; ++k) {
        const int rowl = (k >> 2) * 16 + quad * 4 + (k & 3);
        red[wave * 32 + rowl] = ps[k];
        red[256 + wave * 32 + rowl] = pq[k];
      }
    }
    __syncthreads();
    if (tid < 32) {
      float s = 0.f, q = 0.f;
#pragma unroll
      for (int w = 0; w < 8; ++w) { s += red[w * 32 + tid]; q += red[256 + w * 32 + tid]; }
      const float mu = s * (1.f / 512.f);
      const float var = q * (1.f / 512.f) - mu * mu;
      red[512 + tid] = mu;
      red[544 + tid] = rsqrtf(var + 1e-5f);
    }
    __syncthreads();
#pragma unroll
    for (int i = 0; i < 2; ++i)
#pragma unroll
      for (int r = 0; r < 4; ++r) {
        const int rowl = i * 16 + quad * 4 + r;
        const float mu = red[512 + rowl];
        const float rs = red[544 + rowl];
        const size_t rb = (size_t)(bm + rowl) * D_MODEL;
#pragma unroll
        for (int j = 0; j < 4; ++j) {
          const float y = (x[i][j][r] - mu) * rs * gv[j] + bv[j];
          Hf[rb + col0 + j * 16] = y;
          Hb[rb + col0 + j * 16] = f2b(y);
        }
      }
  } else {
#pragma unroll
    for (int i = 0; i < 2; ++i)
#pragma unroll
      for (int r = 0; r < 4; ++r) {
        const int rowl = i * 16 + quad * 4 + r;
        const size_t rb = (size_t)(bm + rowl) * D_MODEL;
#pragma unroll
        for (int j = 0; j < 4; ++j)
          Cf[rb + col0 + j * 16] = acc[i][j][r] + bi[j];
      }
  }
}

// ---------- MFMA flash attention + fused row-1023 vmean fixup ----------
__global__ __launch_bounds__(256) void attn_mfma_kernel(
    const u16* __restrict__ QKV, const u16* __restrict__ Vt, u16* __restrict__ O)
{
  __shared__ __align__(16) u16 Ks[64 * 64];
  __shared__ __align__(16) u16 Vs[64 * 64];
  __shared__ __align__(16) u16 Ps[4 * 16 * 64];
  const int tid = threadIdx.x;
  const int wave = tid >> 6, lane = tid & 63;
  const int quad = lane >> 4, l15 = lane & 15;
  const int l7 = l15 & 7;
  const int id = blockIdx.x;
  const int bh = id & 63;                           // id%8 == h -> XCD affinity
  const int b = bh >> 3, h = bh & 7;
  const int g = id >> 6;                            // 0..15 == jt0 (block-uniform)
  const int u = g * 4 + wave;                       // q-unit 0..63
  u16* psw = Ps + wave * (16 * 64);
  const size_t qoff = (size_t)b * SEQ * QKV_LD + h * 64;
  const size_t vtb  = (size_t)bh * 64 * SEQ;

  const int sr = tid >> 3, sc = tid & 7;
  const u16* kg0 = QKV + qoff + 512 + (size_t)sr * QKV_LD + sc * 8;
  const u16* kg1 = kg0 + (size_t)32 * QKV_LD;
  const u16* vg0 = Vt + vtb + (size_t)sr * SEQ + sc * 8;
  const u16* vg1 = vg0 + (size_t)32 * SEQ;
  const int sw = (sc ^ (sr & 7)) << 3;              // (sr+32)&7 == sr&7
  u16* ks0 = &Ks[sr * 64 + sw];
  u16* ks1 = &Ks[(sr + 32) * 64 + sw];
  u16* vs0 = &Vs[sr * 64 + sw];
  u16* vs1 = &Vs[(sr + 32) * 64 + sw];

  const u16* qp = QKV + qoff + (size_t)(u * 16 + l15) * QKV_LD + quad * 8;
  const bf16x8 qf0 = *(const bf16x8*)(qp);
  const bf16x8 qf1 = *(const bf16x8*)(qp + 32);

  f32x4 oacc[4] = {};
  float lsum[4] = {0.f, 0.f, 0.f, 0.f};

  uint4v kr0 = *(const uint4v*)(kg0 + (size_t)(g * 64) * QKV_LD);
  uint4v kr1 = *(const uint4v*)(kg1 + (size_t)(g * 64) * QKV_LD);
  uint4v vr0 = *(const uint4v*)(vg0 + g * 64);
  uint4v vr1 = *(const uint4v*)(vg1 + g * 64);

#pragma unroll 1
  for (int jt = g; jt < 16; ++jt) {
    __syncthreads();
    *(uint4v*)ks0 = kr0; *(uint4v*)ks1 = kr1;
    *(uint4v*)vs0 = vr0; *(uint4v*)vs1 = vr1;
    __syncthreads();
    if (jt < 15) {
      kr0 = *(const uint4v*)(kg0 + (size_t)((jt + 1) * 64) * QKV_LD);
      kr1 = *(const uint4v*)(kg1 + (size_t)((jt + 1) * 64) * QKV_LD);
      vr0 = *(const uint4v*)(vg0 + (jt + 1) * 64);
      vr1 = *(const uint4v*)(vg1 + (jt + 1) * 64);
    }
    f32x4 sacc[4] = {};
#pragma unroll
    for (int nt = 0; nt < 4; ++nt) {
      const int key = nt * 16 + l15, k7 = key & 7;
      bf16x8 kb0 = *(const bf16x8*)&Ks[key * 64 + ((quad ^ k7) << 3)];
      bf16x8 kb1 = *(const bf16x8*)&Ks[key * 64 + (((quad + 4) ^ k7) << 3)];
      sacc[nt] = __builtin_amdgcn_mfma_f32_16x16x32_bf16(qf0, kb0, sacc[nt], 0, 0, 0);
      sacc[nt] = __builtin_amdgcn_mfma_f32_16x16x32_bf16(qf1, kb1, sacc[nt], 0, 0, 0);
    }
    const bool diag = (jt == g);
#pragma unroll
    for (int nt = 0; nt < 4; ++nt)
#pragma unroll
      for (int r = 0; r < 4; ++r) {
        float pv = __builtin_amdgcn_exp2f(sacc[nt][r]);
        if (diag) {
          const int i = u * 16 + quad * 4 + r;
          const int j = jt * 64 + nt * 16 + l15;
          pv = (j > i) ? pv : 0.f;                  // keep strictly j > i
        }
        lsum[r] += pv;
        const int qr = quad * 4 + r;
        const int j2 = nt * 16 + l15;
        psw[qr * 64 + (((j2 >> 3) ^ (qr & 7)) << 3) + (j2 & 7)] = f2b(pv);
      }
    bf16x8 pf0 = *(const bf16x8*)&psw[l15 * 64 + (((quad + 0) ^ l7) << 3)];
    bf16x8 pf1 = *(const bf16x8*)&psw[l15 * 64 + (((quad + 4) ^ l7) << 3)];
#pragma unroll
    for (int nt = 0; nt < 4; ++nt) {
      const int d = nt * 16 + l15, d7 = d & 7;
      bf16x8 vb0 = *(const bf16x8*)&Vs[d * 64 + ((quad ^ d7) << 3)];
      bf16x8 vb1 = *(const bf16x8*)&Vs[d * 64 + (((quad + 4) ^ d7) << 3)];
      oacc[nt] = __builtin_amdgcn_mfma_f32_16x16x32_bf16(pf0, vb0, oacc[nt], 0, 0, 0);
      oacc[nt] = __builtin_amdgcn_mfma_f32_16x16x32_bf16(pf1, vb1, oacc[nt], 0, 0, 0);
    }
  }

#pragma unroll
  for (int o = 1; o < 16; o <<= 1)
#pragma unroll
    for (int r = 0; r < 4; ++r) lsum[r] += __shfl_xor(lsum[r], o, 16);
  float rl[4];
#pragma unroll
  for (int r = 0; r < 4; ++r) rl[r] = 1.0f / lsum[r];
#pragma unroll
  for (int nt = 0; nt < 4; ++nt)
#pragma unroll
    for (int r = 0; r < 4; ++r) {
      const int row = u * 16 + quad * 4 + r;
      O[(size_t)(b * SEQ + row) * D_MODEL + h * DKH + nt * 16 + l15] = f2b(oacc[nt][r] * rl[r]);
    }

  // fused vmean: overwrite row S-1 with uniform mean over all keys
  if (g == 15) {
    __syncthreads();   // order after this block's own row-1023 epilogue store
    const int d = tid >> 2, scv = (tid & 3) * 256;
    const u16* pv = Vt + vtb + (size_t)d * SEQ + scv;
    float s = 0.f;
#pragma unroll 8
    for (int i2 = 0; i2 < 256; ++i2) s += b2f(pv[i2]);
    s += __shfl_xor(s, 1, 64);
    s += __shfl_xor(s, 2, 64);
    if ((tid & 3) == 0)
      O[((size_t)b * SEQ + SEQ - 1) * D_MODEL + h * 64 + d] = f2b(s * (1.f / SEQ));
  }
}

// ---------- fused residual add + LayerNorm; T input bf16; writes f32 + bf16 ----------
__global__ __launch_bounds__(256) void add_ln_kernel(
    const float* __restrict__ Hin, const u16* __restrict__ T,
    const float* __restrict__ g, const float* __restrict__ bta,
    float* __restrict__ Hout, u16* __restrict__ Hb)
{
  __shared__ float red[8];
  const int row = blockIdx.x, tid = threadIdx.x;
  const int wave = tid >> 6, lane = tid & 63;
  const size_t base = (size_t)row * D_MODEL;
  const float x0 = Hin[base + tid] + b2f(T[base + tid]);
  const float x1 = Hin[base + tid + 256] + b2f(T[base + tid + 256]);
  float s = x0 + x1;
#pragma unroll
  for (int o = 32; o > 0; o >>= 1) s += __shfl_xor(s, o, 64);
  if (lane == 0) red[wave] = s;
  __syncthreads();
  const float mu = (red[0] + red[1] + red[2] + red[3]) * (1.f / 512.f);
  const float d0 = x0 - mu, d1 = x1 - mu;
  float v = d0 * d0 + d1 * d1;
#pragma unroll
  for (int o = 32; o > 0; o >>= 1) v += __shfl_xor(v, o, 64);
  if (lane == 0) red[4 + wave] = v;
  __syncthreads();
  const float var = (red[4] + red[5] + red[6] + red[7]) * (1.f / 512.f);
  const float rs = rsqrtf(var + 1e-5f);
  const float y0 = d0 * rs * g[tid] + bta[tid];
  const float y1 = d1 * rs * g[tid + 256] + bta[tid + 256];
  Hout[base + tid] = y0;
  Hout[base + tid + 256] = y1;
  Hb[base + tid] = f2b(y0);
  Hb[base + tid + 256] = f2b(y1);
}

extern "C" void kernel_launch(void* const* d_in, const int* in_sizes, int n_in,
                              void* d_out, int out_size, void* d_ws, size_t ws_size,
                              hipStream_t stream) {
  (void)in_sizes; (void)n_in; (void)out_size; (void)ws_size;
  const int*   ids  = (const int*)  d_in[0];
  const float* emb  = (const float*)d_in[1];
  const float* pe   = (const float*)d_in[2];
  const float* Wq   = (const float*)d_in[3];
  const float* bq   = (const float*)d_in[4];
  const float* Wk   = (const float*)d_in[5];
  const float* bk   = (const float*)d_in[6];
  const float* Wv   = (const float*)d_in[7];
  const float* bv   = (const float*)d_in[8];
  const float* Wo   = (const float*)d_in[9];
  const float* bo   = (const float*)d_in[10];
  const float* g1   = (const float*)d_in[11];
  const float* be1  = (const float*)d_in[12];
  const float* W1   = (const float*)d_in[13];
  const float* b1   = (const float*)d_in[14];
  const float* W2   = (const float*)d_in[15];
  const float* b2   = (const float*)d_in[16];
  const float* g2   = (const float*)d_in[17];
  const float* be2  = (const float*)d_in[18];
  const float* Wout = (const float*)d_in[19];
  const float* bout = (const float*)d_in[20];
  float* out = (float*)d_out;

  static int attr_set = 0;
  if (!attr_set) {
    hipFuncSetAttribute(reinterpret_cast<const void*>(&gemm256_kernel<false, true>),
                        hipFuncAttributeMaxDynamicSharedMemorySize, 131072);
    hipFuncSetAttribute(reinterpret_cast<const void*>(&gemm256_kernel<true, false>),
                        hipFuncAttributeMaxDynamicSharedMemorySize, 131072);
    hipFuncSetAttribute(reinterpret_cast<const void*>(&gemm_ln_kernel<true>),
                        hipFuncAttributeMaxDynamicSharedMemorySize, 141568);
    hipFuncSetAttribute(reinterpret_cast<const void*>(&gemm_ln_kernel<false>),
                        hipFuncAttributeMaxDynamicSharedMemorySize, 141568);
    attr_set = 1;
  }

  char* wsp = (char*)d_ws;
  auto alloc = [&](size_t bytes) -> char* {
    char* p = wsp; wsp += (bytes + 255) & ~(size_t)255; return p;
  };
  const size_t dd  = (size_t)D_MODEL * D_MODEL;      // 262144
  const size_t df  = (size_t)D_MODEL * FFN;          // 1048576
  const size_t dq  = (size_t)QKV_LD * D_MODEL;       // 786432
  u16* wqkv_t = (u16*)alloc(NLAYER * dq * 2);
  u16* wo_t   = (u16*)alloc(NLAYER * dd * 2);
  u16* w1_t   = (u16*)alloc(NLAYER * df * 2);
  u16* w2_t   = (u16*)alloc(NLAYER * df * 2);
  u16* wout_t = (u16*)alloc(dd * 2);
  float* bqkv = (float*)alloc(NLAYER * QKV_LD * 4);
  float* hf   = (float*)alloc((size_t)MROWS * D_MODEL * 4);
  u16*   hb   = (u16*)  alloc((size_t)MROWS * D_MODEL * 2);
  u16*   qkvb = (u16*)  alloc((size_t)MROWS * QKV_LD * 2);   // 24 MB
  u16*   ob   = (u16*)  alloc((size_t)MROWS * D_MODEL * 2);  // 8 MB
  u16*   vt   = (u16*)  alloc((size_t)BATCH * NHEAD * DKH * SEQ * 2);
  u16*   tb   = (u16*)  alloc((size_t)MROWS * D_MODEL * 2);  // bf16 FFN2 out buffer
  u16*   mid  = qkvb;  // FFN mid [8192,2048] aliases qkvb+ob (dead by FFN1; stream-ordered)

  dim3 tb8(32, 8);
  transpose_cvt_kernel<<<dim3(16, 16, NLAYER), tb8, 0, stream>>>(Wq, wqkv_t,            512, 512,  dq, SCALE_LOG2E);
  transpose_cvt_kernel<<<dim3(16, 16, NLAYER), tb8, 0, stream>>>(Wk, wqkv_t + 512*512,  512, 512,  dq, 1.f);
  transpose_cvt_kernel<<<dim3(16, 16, NLAYER), tb8, 0, stream>>>(Wv, wqkv_t + 1024*512, 512, 512,  dq, 1.f);
  transpose_cvt_kernel<<<dim3(16, 16, NLAYER), tb8, 0, stream>>>(Wo, wo_t,   512, 512,  dd, 1.f);
  transpose_cvt_kernel<<<dim3(64, 16, NLAYER), tb8, 0, stream>>>(W1, w1_t,   512, 2048, df, 1.f);
  transpose_cvt_kernel<<<dim3(16, 64, NLAYER), tb8, 0, stream>>>(W2, w2_t,   2048, 512, df, 1.f);
  transpose_cvt_kernel<<<dim3(16, 16, 1),      tb8, 0, stream>>>(Wout, wout_t, 512, 512, dd, 1.f);
  concat_bias_kernel<<<NLAYER, 256, 0, stream>>>(bq, bk, bv, bqkv);

  embed_kernel<<<MROWS, 256, 0, stream>>>(ids, emb, pe, hf, hb);

  for (int l = 0; l < NLAYER; ++l) {
    gemm256_kernel<false, true><<<dim3(32, 6), 512, 131072, stream>>>(
        hb, wqkv_t + l * dq, bqkv + l * QKV_LD, qkvb, vt, MROWS, QKV_LD, 512);
    attn_mfma_kernel<<<1024, 256, 0, stream>>>(qkvb, vt, ob);
    gemm_ln_kernel<true><<<256, 512, 141568, stream>>>(
        ob, wo_t + l * dd, bo + l * 512, g1 + l * 512, be1 + l * 512,
        hf, hb, nullptr, 512);
    gemm256_kernel<true, false><<<dim3(32, 8), 512, 131072, stream>>>(
        hb, w1_t + l * df, b1 + l * 2048, mid, nullptr, MROWS, 2048, 512);
    gemm_kernel<64, false, false, true, false><<<dim3(128, 4), 256, 0, stream>>>(
        mid, w2_t + l * df, b2 + l * 512, nullptr, tb, nullptr, MROWS, 512, 2048);
    add_ln_kernel<<<MROWS, 256, 0, stream>>>(hf, tb, g2 + l * 512, be2 + l * 512, hf, hb);
  }
  gemm_ln_kernel<false><<<256, 512, 141568, stream>>>(
      hb, wout_t, bout, nullptr, nullptr, nullptr, nullptr, out, 512);
}

// Round 8
// 967.383 us; speedup vs baseline: 1.0701x; 1.0019x over previous
//
#include <hip/hip_runtime.h>

typedef unsigned short u16;
typedef __attribute__((ext_vector_type(8))) short bf16x8;   // 8 bf16 (4 VGPRs)
typedef __attribute__((ext_vector_type(4))) float f32x4;
typedef __attribute__((ext_vector_type(4))) unsigned int uint4v;
typedef __attribute__((ext_vector_type(4))) unsigned short us4;

#define NLAYER 6
#define D_MODEL 512
#define NHEAD 8
#define DKH 64
#define SEQ 1024
#define BATCH 8
#define FFN 2048
#define MROWS (BATCH * SEQ)  /* 8192 */
#define QKV_LD 1536
#define SCALE_LOG2E 0.18033688011112042f  /* (1/sqrt(64)) * log2(e), folded into Wq/bq */

__device__ __forceinline__ float b2f(u16 u) {
  union { unsigned u32; float f; } x; x.u32 = ((unsigned)u) << 16; return x.f;
}
__device__ __forceinline__ u16 f2b(float f) {
  union { float f; unsigned u; } x; x.f = f;
  unsigned r = x.u + 0x7FFFu + ((x.u >> 16) & 1u);   // RNE
  return (u16)(r >> 16);
}
// async global->LDS, 16B per lane; LDS dest = wave-uniform base + lane*16 (m97)
__device__ __forceinline__ void gld16(const u16* g, u16* l) {
  __builtin_amdgcn_global_load_lds(
      (const __attribute__((address_space(1))) unsigned int*)g,
      (__attribute__((address_space(3))) unsigned int*)l, 16, 0, 0);
}
// raw workgroup barrier (NO vmcnt/lgkmcnt drain) + compiler memory fences
__device__ __forceinline__ void barrier_raw() {
  asm volatile("" ::: "memory");
  __builtin_amdgcn_s_barrier();
  asm volatile("" ::: "memory");
}

// ---------- weight transpose + f32->bf16 (scale folds attn score scale into Wq) ----------
__global__ __launch_bounds__(256) void transpose_cvt_kernel(
    const float* __restrict__ src, u16* __restrict__ dst, int K, int N, size_t dstZ,
    float scale)
{
  __shared__ float t[32][33];
  const int z = blockIdx.z;
  src += (size_t)z * K * N;
  dst += (size_t)z * dstZ;
  const int n0 = blockIdx.x * 32, k0 = blockIdx.y * 32;
  const int tx = threadIdx.x, ty = threadIdx.y;  // 32 x 8
#pragma unroll
  for (int i = 0; i < 32; i += 8)
    t[ty + i][tx] = src[(size_t)(k0 + ty + i) * N + n0 + tx];
  __syncthreads();
#pragma unroll
  for (int i = 0; i < 32; i += 8)
    dst[(size_t)(n0 + ty + i) * K + k0 + tx] = f2b(t[tx][ty + i] * scale);
}

// ---------- concat per-layer q/k/v biases into [L][1536]; bq pre-scaled ----------
__global__ __launch_bounds__(256) void concat_bias_kernel(
    const float* __restrict__ bq, const float* __restrict__ bk,
    const float* __restrict__ bv, float* __restrict__ dst)
{
  const int l = blockIdx.x, t = threadIdx.x;
#pragma unroll
  for (int j = t; j < 512; j += 256) {
    dst[l * QKV_LD + j]        = bq[l * 512 + j] * SCALE_LOG2E;
    dst[l * QKV_LD + 512 + j]  = bk[l * 512 + j];
    dst[l * QKV_LD + 1024 + j] = bv[l * 512 + j];
  }
}

// ---------- embedding: h = emb[ids]*sqrt(D) + pe[s] ----------
__global__ __launch_bounds__(256) void embed_kernel(
    const int* __restrict__ ids, const float* __restrict__ emb,
    const float* __restrict__ pe, float* __restrict__ Hf, u16* __restrict__ Hb)
{
  const int row = blockIdx.x;
  const int s = row & (SEQ - 1);
  const int id = ids[row];
  const int tid = threadIdx.x;
#pragma unroll
  for (int u = 0; u < 2; ++u) {
    const int d = tid + u * 256;
    float v = emb[(size_t)id * D_MODEL + d] * 22.62741699796952f + pe[(size_t)s * D_MODEL + d];
    Hf[(size_t)row * D_MODEL + d] = v;
    Hb[(size_t)row * D_MODEL + d] = f2b(v);
  }
}

// ---------- 2-phase bf16 MFMA GEMM (N-split, high occupancy): C = A @ Bt^T + bias ----------
// BMTx128 tile, BK=64, 2-buf gld16 staging. 48 KB LDS -> 3 blocks/CU, 12
// waves/CU: TLP hides the staging latency. Used for FFN2 (grid 128x4).
template<int BMT, bool RELU, bool OUTF, bool OUTB, bool VT>
__global__ __launch_bounds__(256) void gemm_kernel(
    const u16* __restrict__ A, const u16* __restrict__ Bt,
    const float* __restrict__ bias,
    float* __restrict__ Cf, u16* __restrict__ Cb, u16* __restrict__ Vtp,
    int M, int N, int K)
{
  constexpr int IT = BMT / 32;                 // 2 (BMT=64)
  constexpr int AHALF = BMT * 64;              // u16 per A buffer
  constexpr int BHALF = 128 * 64;              // u16 per B buffer
  __shared__ __align__(16) u16 As[2 * AHALF];
  __shared__ __align__(16) u16 Bs[2 * BHALF];
  const int tid = threadIdx.x;
  const int bm = blockIdx.x * BMT, bn = blockIdx.y * 128;
  const int wave = tid >> 6, lane = tid & 63;
  const int lm = lane & 15, quad = lane >> 4;
  const int wm = (wave & 1) * (BMT / 2), wn = (wave >> 1) * 64;

  const int sr = tid >> 3;                     // 0..31
  const int sc = (tid & 7) ^ (sr & 7);         // pre-swizzled source chunk
  const u16* Ap = A  + (size_t)(bm + sr) * K + sc * 8;
  const u16* Bp = Bt + (size_t)(bn + sr) * K + sc * 8;
  u16* lA = As + wave * 512;
  u16* lB = Bs + wave * 512;

  f32x4 acc[IT][4] = {};

  const int nt = K >> 6;
  auto stage = [&](int buf, int t) {
    const size_t ko = (size_t)t << 6;
#pragma unroll
    for (int p = 0; p < BMT / 32; ++p)
      gld16(Ap + (size_t)(p * 32) * K + ko, lA + buf * AHALF + p * 2048);
#pragma unroll
    for (int p = 0; p < 4; ++p)
      gld16(Bp + (size_t)(p * 32) * K + ko, lB + buf * BHALF + p * 2048);
  };

  stage(0, 0);
  __syncthreads();

  for (int t = 0; t < nt; ++t) {
    const int cur = t & 1;
    if (t + 1 < nt) stage(cur ^ 1, t + 1);
    const u16* as = As + cur * AHALF;
    const u16* bs = Bs + cur * BHALF;
#pragma unroll
    for (int kh = 0; kh < 2; ++kh) {
      bf16x8 af[IT], bg[4];
#pragma unroll
      for (int i = 0; i < IT; ++i) {
        const int row = wm + i * 16 + lm;
        af[i] = *(const bf16x8*)&as[row * 64 + (((kh * 4 + quad) ^ (row & 7)) << 3)];
      }
#pragma unroll
      for (int j = 0; j < 4; ++j) {
        const int row = wn + j * 16 + lm;
        bg[j] = *(const bf16x8*)&bs[row * 64 + (((kh * 4 + quad) ^ (row & 7)) << 3)];
      }
#pragma unroll
      for (int i = 0; i < IT; ++i)
#pragma unroll
        for (int j = 0; j < 4; ++j)
          acc[i][j] = __builtin_amdgcn_mfma_f32_16x16x32_bf16(af[i], bg[j], acc[i][j], 0, 0, 0);
    }
    __syncthreads();
  }

  const int mbase = bm + wm + quad * 4;
  const int nbase = bn + wn + lm;
#pragma unroll
  for (int i = 0; i < IT; ++i) {
#pragma unroll
    for (int j = 0; j < 4; ++j) {
      const int n = nbase + j * 16;
      const float bv = bias[n];
      float vv[4];
#pragma unroll
      for (int r = 0; r < 4; ++r) {
        float v = acc[i][j][r] + bv;
        if (RELU) v = fmaxf(v, 0.f);
        vv[r] = v;
      }
      if (VT && n >= 1024) {
        const int hh = (n - 1024) >> 6, d = (n - 1024) & 63;
        const int mm = mbase + i * 16;
        const int bb = mm >> 10, ss = mm & 1023;
        us4 pk;
#pragma unroll
        for (int r = 0; r < 4; ++r) pk[r] = f2b(vv[r]);
        *(us4*)&Vtp[(((size_t)(bb * NHEAD + hh)) * 64 + d) * SEQ + ss] = pk;
      } else {
#pragma unroll
        for (int r = 0; r < 4; ++r) {
          const int m = mbase + i * 16 + r;
          if (OUTF) Cf[(size_t)m * N + n] = vv[r];
          if (OUTB) Cb[(size_t)m * N + n] = f2b(vv[r]);
        }
      }
    }
  }
}

// ---------- 256x256 pipelined bf16 GEMM: BK=32, 4-deep LDS ring, counted vmcnt ----------
// T4 applied to the proven 256^2 shape: stage runs 2 tiles ahead; boundary
// waits vmcnt(4) (= tile t+1's loads stay in flight) -- the load pipe never
// drains until the last tile. 1 raw barrier/tile. LDS 128 KB: A ring
// 4x[128 lines][64 u16] + B ring same. Logical row r, k-chunk q (8 bf16)
// stored at line r>>1, chunk clog = q + 4*(r&1), phys chunk = clog ^ (line&7)
// -- packed-pair layout keeps 128B-line geometry; per-16-lane quarter-wave
// (the HW conflict granularity) each frag read is 2 lanes/bank = free (m136).
// Buffer reuse: stage(t+2) overwrites ring[t-2], last read 2 barriers ago.
// K-chunks ascending 32-wide -> accumulation order identical to BK=64 kernel.
template<bool RELU, bool VT>
__global__ __launch_bounds__(512, 2) void gemm256_kernel(
    const u16* __restrict__ A, const u16* __restrict__ Bt,
    const float* __restrict__ bias,
    u16* __restrict__ Cb, u16* __restrict__ Vtp,
    int M, int N, int K)
{
  extern __shared__ __align__(16) u16 smem[];
  u16* ringA = smem;            // [4][8192] u16 = 64 KB
  u16* ringB = smem + 32768;    // [4][8192] u16 = 64 KB
  const int tid = threadIdx.x;
  const int wave = tid >> 6, lane = tid & 63;
  const int lm = lane & 15, quad = lane >> 4;
  const int wm = wave >> 2, wn = wave & 3;     // 2 x 4 wave grid
  const int bm = blockIdx.x * 256, bn = blockIdx.y * 256;

  // staging source precompute: for g in {0,1}, u = wave*128 + g*64 + lane;
  // line = u>>3, cph = u&7, clog = cph ^ (line&7), r = 2*line + (clog>>2),
  // kq = clog & 3. src = X + (base + r)*K + kq*8 (+ t*32 per call).
  const u16* srcA[2];
  const u16* srcB[2];
  u16* dstA[2];
  u16* dstB[2];
#pragma unroll
  for (int g = 0; g < 2; ++g) {
    const int u = wave * 128 + g * 64 + lane;
    const int line = u >> 3, cph = u & 7;
    const int clog = cph ^ (line & 7);
    const int r = 2 * line + (clog >> 2);
    const int kq = clog & 3;
    srcA[g] = A  + (size_t)(bm + r) * K + kq * 8;
    srcB[g] = Bt + (size_t)(bn + r) * K + kq * 8;
    dstA[g] = ringA + wave * 1024 + g * 512;   // lane*16B implicit in gld16
    dstB[g] = ringB + wave * 1024 + g * 512;
  }

  const int NT = K >> 5;
  auto stage = [&](int buf, int t) {
    const size_t ko = (size_t)t << 5;
#pragma unroll
    for (int g = 0; g < 2; ++g) gld16(srcA[g] + ko, dstA[g] + buf * 8192);
#pragma unroll
    for (int g = 0; g < 2; ++g) gld16(srcB[g] + ko, dstB[g] + buf * 8192);
  };

  f32x4 acc[8][4] = {};

  stage(0, 0);
  stage(1, 1);

  // frag addressing (lane-constant parts): line&7 = (lm>>1)&7 for all frags
  const int cs = ((quad + ((lm & 1) << 2)) ^ ((lm >> 1) & 7)) << 3;  // u16
  const int aoff = (wm * 64 + (lm >> 1)) * 64 + cs;   // + i*512
  const int boff = (wn * 32 + (lm >> 1)) * 64 + cs;   // + j*512

#pragma unroll 1
  for (int t = 0; t < NT; ++t) {
    if (t + 1 < NT) asm volatile("s_waitcnt vmcnt(4)" ::: "memory");
    else            asm volatile("s_waitcnt vmcnt(0)" ::: "memory");
    barrier_raw();                            // all waves: tile t resident
    if (t + 2 < NT) stage((t + 2) & 3, t + 2); // overwrites ring[t-2]: safe
    const u16* as_ = ringA + (t & 3) * 8192 + aoff;
    const u16* bs_ = ringB + (t & 3) * 8192 + boff;
    bf16x8 af[8], bg[4];
#pragma unroll
    for (int i = 0; i < 8; ++i) af[i] = *(const bf16x8*)&as_[i * 512];
#pragma unroll
    for (int j = 0; j < 4; ++j) bg[j] = *(const bf16x8*)&bs_[j * 512];
    __builtin_amdgcn_s_setprio(1);
#pragma unroll
    for (int i = 0; i < 8; ++i)
#pragma unroll
      for (int j = 0; j < 4; ++j)
        acc[i][j] = __builtin_amdgcn_mfma_f32_16x16x32_bf16(af[i], bg[j], acc[i][j], 0, 0, 0);
    __builtin_amdgcn_s_setprio(0);
  }

  // epilogue: D row = quad*4+reg, col = lm (unchanged from proven kernel)
  const int mbase = bm + wm * 128 + quad * 4;
  const int nbase = bn + wn * 64 + lm;
#pragma unroll
  for (int i = 0; i < 8; ++i) {
#pragma unroll
    for (int j = 0; j < 4; ++j) {
      const int n = nbase + j * 16;
      const float bv = bias[n];
      float vv[4];
#pragma unroll
      for (int r = 0; r < 4; ++r) {
        float v = acc[i][j][r] + bv;
        if (RELU) v = fmaxf(v, 0.f);
        vv[r] = v;
      }
      if (VT && n >= 1024) {
        const int hh = (n - 1024) >> 6, d = (n - 1024) & 63;
        const int mm = mbase + i * 16;               // 4-aligned
        const int bb = mm >> 10, ss = mm & 1023;
        us4 pk;
#pragma unroll
        for (int r = 0; r < 4; ++r) pk[r] = f2b(vv[r]);
        *(us4*)&Vtp[(((size_t)(bb * NHEAD + hh)) * 64 + d) * SEQ + ss] = pk;
      } else {
#pragma unroll
        for (int r = 0; r < 4; ++r) {
          const int m = mbase + i * 16 + r;
          Cb[(size_t)m * N + n] = f2b(vv[r]);
        }
      }
    }
  }
}

// ---------- full-row GEMM (N=512, K=512) with fused residual+LayerNorm epilogue ----------
// R3-exact BM=32 kernel. Only used where K=512 (Wo, Wout).
template<bool LN>
__global__ __launch_bounds__(512, 2) void gemm_ln_kernel(
    const u16* __restrict__ A, const u16* __restrict__ Bt,
    const float* __restrict__ bias,
    const float* __restrict__ gw, const float* __restrict__ bw,
    float* __restrict__ Hf, u16* __restrict__ Hb, float* __restrict__ Cf,
    int K)
{
  extern __shared__ __align__(16) u16 smem[];
  u16* Asm = smem;
  u16* Bsm = smem + 4096;
  float* red = (float*)(smem + 69632);  // sred[256] qred[256] mu[32] rs[32]
  const int tid = threadIdx.x;
  const int wave = tid >> 6, lane = tid & 63;
  const int lm = lane & 15, quad = lane >> 4, l7 = lm & 7;
  const int bm = blockIdx.x * 32;

  const int srow = tid >> 3;                   // 0..63
  const int scg = (tid & 7) ^ (srow & 7);      // pre-swizzled source chunk
  const u16* Ap = A  + (size_t)(bm + srow) * K + scg * 8;  // used rows <32
  const u16* Bp = Bt + (size_t)srow * K + scg * 8;
  u16* uA = Asm + wave * 512;                  // waves 0..3 stage A
  u16* uB = Bsm + wave * 512;

  f32x4 acc[2][4] = {};
  const int NT = K >> 6;
  auto stage = [&](int buf, int t) {
    const size_t ko = (size_t)t << 6;
    if (wave < 4) gld16(Ap + ko, uA + buf * 2048);
#pragma unroll
    for (int p = 0; p < 8; ++p)
      gld16(Bp + (size_t)(p * 64) * K + ko, uB + buf * 32768 + p * 4096);
  };

  stage(0, 0);
  __syncthreads();

#pragma unroll 1
  for (int t = 0; t < NT; ++t) {
    const int cur = t & 1;
    if (t + 1 < NT) stage(cur ^ 1, t + 1);
    const u16* as_ = Asm + cur * 2048 + lm * 64;
    const u16* bs_ = Bsm + cur * 32768 + (wave * 64 + lm) * 64;
#pragma unroll
    for (int kh = 0; kh < 2; ++kh) {
      const int slot = ((kh * 4 + quad) ^ l7) << 3;
      bf16x8 af[2], bg[4];
      af[0] = *(const bf16x8*)&as_[slot];
      af[1] = *(const bf16x8*)&as_[1024 + slot];
#pragma unroll
      for (int j = 0; j < 4; ++j)
        bg[j] = *(const bf16x8*)&bs_[j * 1024 + slot];
#pragma unroll
      for (int i = 0; i < 2; ++i)
#pragma unroll
        for (int j = 0; j < 4; ++j)
          acc[i][j] = __builtin_amdgcn_mfma_f32_16x16x32_bf16(af[i], bg[j], acc[i][j], 0, 0, 0);
    }
    __syncthreads();
  }

  const int col0 = wave * 64 + lm;
  float bi[4];
#pragma unroll
  for (int j = 0; j < 4; ++j) bi[j] = bias[col0 + j * 16];

  if (LN) {
    float gv[4], bv[4];
#pragma unroll
    for (int j = 0; j < 4; ++j) { gv[j] = gw[col0 + j * 16]; bv[j] = bw[col0 + j * 16]; }
    float x[2][4][4];
    float ps[8], pq[8];
#pragma unroll
    for (int k = 0; k < 8; ++k) { ps[k] = 0.f; pq[k] = 0.f; }
#pragma unroll
    for (int i = 0; i < 2; ++i)
#pragma unroll
      for (int r = 0; r < 4; ++r) {
        const int rowl = i * 16 + quad * 4 + r;
        const size_t rb = (size_t)(bm + rowl) * D_MODEL;
#pragma unroll
        for (int j = 0; j < 4; ++j) {
          float xv = acc[i][j][r] + bi[j] + Hf[rb + col0 + j * 16];
          x[i][j][r] = xv;
          ps[i * 4 + r] += xv;
          pq[i * 4 + r] += xv * xv;
        }
      }
#pragma unroll
    for (int o = 1; o < 16; o <<= 1)
#pragma unroll
      for (int k = 0; k < 8; ++k) {
        ps[k] += __shfl_xor(ps[k], o, 16);
        pq[k] += __shfl_xor(pq[k], o, 16);
      }
    if (lm == 0) {
#pragma unroll
      for (int k = 0; k < 8; ++k) {
        const int rowl = (k >> 2) * 16 + quad * 4 + (k & 3);
        red[wave * 32 + rowl] = ps[k];
        red[256 + wave * 32 + rowl] = pq[k];
      }
    }
    __syncthreads();
    if (tid < 32) {
      float s = 0.f, q = 0.f;
#pragma unroll
      for (int w = 0; w < 8; ++w) { s += red[w * 32 + tid]; q += red[256 + w * 32 + tid]; }
      const float mu = s * (1.f / 512.f);
      const float var = q * (1.f / 512.f) - mu * mu;
      red[512 + tid] = mu;
      red[544 + tid] = rsqrtf(var + 1e-5f);
    }
    __syncthreads();
#pragma unroll
    for (int i = 0; i < 2; ++i)
#pragma unroll
      for (int r = 0; r < 4; ++r) {
        const int rowl = i * 16 + quad * 4 + r;
        const float mu = red[512 + rowl];
        const float rs = red[544 + rowl];
        const size_t rb = (size_t)(bm + rowl) * D_MODEL;
#pragma unroll
        for (int j = 0; j < 4; ++j) {
          const float y = (x[i][j][r] - mu) * rs * gv[j] + bv[j];
          Hf[rb + col0 + j * 16] = y;
          Hb[rb + col0 + j * 16] = f2b(y);
        }
      }
  } else {
#pragma unroll
    for (int i = 0; i < 2; ++i)
#pragma unroll
      for (int r = 0; r < 4; ++r) {
        const int rowl = i * 16 + quad * 4 + r;
        const size_t rb = (size_t)(bm + rowl) * D_MODEL;
#pragma unroll
        for (int j = 0; j < 4; ++j)
          Cf[rb + col0 + j * 16] = acc[i][j][r] + bi[j];
      }
  }
}

// ---------- MFMA flash attention + fused row-1023 vmean fixup ----------
__global__ __launch_bounds__(256) void attn_mfma_kernel(
    const u16* __restrict__ QKV, const u16* __restrict__ Vt, u16* __restrict__ O)
{
  __shared__ __align__(16) u16 Ks[64 * 64];
  __shared__ __align__(16) u16 Vs[64 * 64];
  __shared__ __align__(16) u16 Ps[4 * 16 * 64];
  const int tid = threadIdx.x;
  const int wave = tid >> 6, lane = tid & 63;
  const int quad = lane >> 4, l15 = lane & 15;
  const int l7 = l15 & 7;
  const int id = blockIdx.x;
  const int bh = id & 63;                           // id%8 == h -> XCD affinity
  const int b = bh >> 3, h = bh & 7;
  const int g = id >> 6;                            // 0..15 == jt0 (block-uniform)
  const int u = g * 4 + wave;                       // q-unit 0..63
  u16* psw = Ps + wave * (16 * 64);
  const size_t qoff = (size_t)b * SEQ * QKV_LD + h * 64;
  const size_t vtb  = (size_t)bh * 64 * SEQ;

  const int sr = tid >> 3, sc = tid & 7;
  const u16* kg0 = QKV + qoff + 512 + (size_t)sr * QKV_LD + sc * 8;
  const u16* kg1 = kg0 + (size_t)32 * QKV_LD;
  const u16* vg0 = Vt + vtb + (size_t)sr * SEQ + sc * 8;
  const u16* vg1 = vg0 + (size_t)32 * SEQ;
  const int sw = (sc ^ (sr & 7)) << 3;              // (sr+32)&7 == sr&7
  u16* ks0 = &Ks[sr * 64 + sw];
  u16* ks1 = &Ks[(sr + 32) * 64 + sw];
  u16* vs0 = &Vs[sr * 64 + sw];
  u16* vs1 = &Vs[(sr + 32) * 64 + sw];

  const u16* qp = QKV + qoff + (size_t)(u * 16 + l15) * QKV_LD + quad * 8;
  const bf16x8 qf0 = *(const bf16x8*)(qp);
  const bf16x8 qf1 = *(const bf16x8*)(qp + 32);

  f32x4 oacc[4] = {};
  float lsum[4] = {0.f, 0.f, 0.f, 0.f};

  uint4v kr0 = *(const uint4v*)(kg0 + (size_t)(g * 64) * QKV_LD);
  uint4v kr1 = *(const uint4v*)(kg1 + (size_t)(g * 64) * QKV_LD);
  uint4v vr0 = *(const uint4v*)(vg0 + g * 64);
  uint4v vr1 = *(const uint4v*)(vg1 + g * 64);

#pragma unroll 1
  for (int jt = g; jt < 16; ++jt) {
    __syncthreads();
    *(uint4v*)ks0 = kr0; *(uint4v*)ks1 = kr1;
    *(uint4v*)vs0 = vr0; *(uint4v*)vs1 = vr1;
    __syncthreads();
    if (jt < 15) {
      kr0 = *(const uint4v*)(kg0 + (size_t)((jt + 1) * 64) * QKV_LD);
      kr1 = *(const uint4v*)(kg1 + (size_t)((jt + 1) * 64) * QKV_LD);
      vr0 = *(const uint4v*)(vg0 + (jt + 1) * 64);
      vr1 = *(const uint4v*)(vg1 + (jt + 1) * 64);
    }
    f32x4 sacc[4] = {};
#pragma unroll
    for (int nt = 0; nt < 4; ++nt) {
      const int key = nt * 16 + l15, k7 = key & 7;
      bf16x8 kb0 = *(const bf16x8*)&Ks[key * 64 + ((quad ^ k7) << 3)];
      bf16x8 kb1 = *(const bf16x8*)&Ks[key * 64 + (((quad + 4) ^ k7) << 3)];
      sacc[nt] = __builtin_amdgcn_mfma_f32_16x16x32_bf16(qf0, kb0, sacc[nt], 0, 0, 0);
      sacc[nt] = __builtin_amdgcn_mfma_f32_16x16x32_bf16(qf1, kb1, sacc[nt], 0, 0, 0);
    }
    const bool diag = (jt == g);
#pragma unroll
    for (int nt = 0; nt < 4; ++nt)
#pragma unroll
      for (int r = 0; r < 4; ++r) {
        float pv = __builtin_amdgcn_exp2f(sacc[nt][r]);
        if (diag) {
          const int i = u * 16 + quad * 4 + r;
          const int j = jt * 64 + nt * 16 + l15;
          pv = (j > i) ? pv : 0.f;                  // keep strictly j > i
        }
        lsum[r] += pv;
        const int qr = quad * 4 + r;
        const int j2 = nt * 16 + l15;
        psw[qr * 64 + (((j2 >> 3) ^ (qr & 7)) << 3) + (j2 & 7)] = f2b(pv);
      }
    bf16x8 pf0 = *(const bf16x8*)&psw[l15 * 64 + (((quad + 0) ^ l7) << 3)];
    bf16x8 pf1 = *(const bf16x8*)&psw[l15 * 64 + (((quad + 4) ^ l7) << 3)];
#pragma unroll
    for (int nt = 0; nt < 4; ++nt) {
      const int d = nt * 16 + l15, d7 = d & 7;
      bf16x8 vb0 = *(const bf16x8*)&Vs[d * 64 + ((quad ^ d7) << 3)];
      bf16x8 vb1 = *(const bf16x8*)&Vs[d * 64 + (((quad + 4) ^ d7) << 3)];
      oacc[nt] = __builtin_amdgcn_mfma_f32_16x16x32_bf16(pf0, vb0, oacc[nt], 0, 0, 0);
      oacc[nt] = __builtin_amdgcn_mfma_f32_16x16x32_bf16(pf1, vb1, oacc[nt], 0, 0, 0);
    }
  }

#pragma unroll
  for (int o = 1; o < 16; o <<= 1)
#pragma unroll
    for (int r = 0; r < 4; ++r) lsum[r] += __shfl_xor(lsum[r], o, 16);
  float rl[4];
#pragma unroll
  for (int r = 0; r < 4; ++r) rl[r] = 1.0f / lsum[r];
#pragma unroll
  for (int nt = 0; nt < 4; ++nt)
#pragma unroll
    for (int r = 0; r < 4; ++r) {
      const int row = u * 16 + quad * 4 + r;
      O[(size_t)(b * SEQ + row) * D_MODEL + h * DKH + nt * 16 + l15] = f2b(oacc[nt][r] * rl[r]);
    }

  // fused vmean: overwrite row S-1 with uniform mean over all keys
  if (g == 15) {
    __syncthreads();   // order after this block's own row-1023 epilogue store
    const int d = tid >> 2, scv = (tid & 3) * 256;
    const u16* pv = Vt + vtb + (size_t)d * SEQ + scv;
    float s = 0.f;
#pragma unroll 8
    for (int i2 = 0; i2 < 256; ++i2) s += b2f(pv[i2]);
    s += __shfl_xor(s, 1, 64);
    s += __shfl_xor(s, 2, 64);
    if ((tid & 3) == 0)
      O[((size_t)b * SEQ + SEQ - 1) * D_MODEL + h * 64 + d] = f2b(s * (1.f / SEQ));
  }
}

// ---------- fused residual add + LayerNorm; T input bf16; writes f32 + bf16 ----------
__global__ __launch_bounds__(256) void add_ln_kernel(
    const float* __restrict__ Hin, const u16* __restrict__ T,
    const float* __restrict__ g, const float* __restrict__ bta,
    float* __restrict__ Hout, u16* __restrict__ Hb)
{
  __shared__ float red[8];
  const int row = blockIdx.x, tid = threadIdx.x;
  const int wave = tid >> 6, lane = tid & 63;
  const size_t base = (size_t)row * D_MODEL;
  const float x0 = Hin[base + tid] + b2f(T[base + tid]);
  const float x1 = Hin[base + tid + 256] + b2f(T[base + tid + 256]);
  float s = x0 + x1;
#pragma unroll
  for (int o = 32; o > 0; o >>= 1) s += __shfl_xor(s, o, 64);
  if (lane == 0) red[wave] = s;
  __syncthreads();
  const float mu = (red[0] + red[1] + red[2] + red[3]) * (1.f / 512.f);
  const float d0 = x0 - mu, d1 = x1 - mu;
  float v = d0 * d0 + d1 * d1;
#pragma unroll
  for (int o = 32; o > 0; o >>= 1) v += __shfl_xor(v, o, 64);
  if (lane == 0) red[4 + wave] = v;
  __syncthreads();
  const float var = (red[4] + red[5] + red[6] + red[7]) * (1.f / 512.f);
  const float rs = rsqrtf(var + 1e-5f);
  const float y0 = d0 * rs * g[tid] + bta[tid];
  const float y1 = d1 * rs * g[tid + 256] + bta[tid + 256];
  Hout[base + tid] = y0;
  Hout[base + tid + 256] = y1;
  Hb[base + tid] = f2b(y0);
  Hb[base + tid + 256] = f2b(y1);
}

extern "C" void kernel_launch(void* const* d_in, const int* in_sizes, int n_in,
                              void* d_out, int out_size, void* d_ws, size_t ws_size,
                              hipStream_t stream) {
  (void)in_sizes; (void)n_in; (void)out_size; (void)ws_size;
  const int*   ids  = (const int*)  d_in[0];
  const float* emb  = (const float*)d_in[1];
  const float* pe   = (const float*)d_in[2];
  const float* Wq   = (const float*)d_in[3];
  const float* bq   = (const float*)d_in[4];
  const float* Wk   = (const float*)d_in[5];
  const float* bk   = (const float*)d_in[6];
  const float* Wv   = (const float*)d_in[7];
  const float* bv   = (const float*)d_in[8];
  const float* Wo   = (const float*)d_in[9];
  const float* bo   = (const float*)d_in[10];
  const float* g1   = (const float*)d_in[11];
  const float* be1  = (const float*)d_in[12];
  const float* W1   = (const float*)d_in[13];
  const float* b1   = (const float*)d_in[14];
  const float* W2   = (const float*)d_in[15];
  const float* b2   = (const float*)d_in[16];
  const float* g2   = (const float*)d_in[17];
  const float* be2  = (const float*)d_in[18];
  const float* Wout = (const float*)d_in[19];
  const float* bout = (const float*)d_in[20];
  float* out = (float*)d_out;

  static int attr_set = 0;
  if (!attr_set) {
    hipFuncSetAttribute(reinterpret_cast<const void*>(&gemm256_kernel<false, true>),
                        hipFuncAttributeMaxDynamicSharedMemorySize, 131072);
    hipFuncSetAttribute(reinterpret_cast<const void*>(&gemm256_kernel<true, false>),
                        hipFuncAttributeMaxDynamicSharedMemorySize, 131072);
    hipFuncSetAttribute(reinterpret_cast<const void*>(&gemm_ln_kernel<true>),
                        hipFuncAttributeMaxDynamicSharedMemorySize, 141568);
    hipFuncSetAttribute(reinterpret_cast<const void*>(&gemm_ln_kernel<false>),
                        hipFuncAttributeMaxDynamicSharedMemorySize, 141568);
    attr_set = 1;
  }

  char* wsp = (char*)d_ws;
  auto alloc = [&](size_t bytes) -> char* {
    char* p = wsp; wsp += (bytes + 255) & ~(size_t)255; return p;
  };
  const size_t dd  = (size_t)D_MODEL * D_MODEL;      // 262144
  const size_t df  = (size_t)D_MODEL * FFN;          // 1048576
  const size_t dq  = (size_t)QKV_LD * D_MODEL;       // 786432
  u16* wqkv_t = (u16*)alloc(NLAYER * dq * 2);
  u16* wo_t   = (u16*)alloc(NLAYER * dd * 2);
  u16* w1_t   = (u16*)alloc(NLAYER * df * 2);
  u16* w2_t   = (u16*)alloc(NLAYER * df * 2);
  u16* wout_t = (u16*)alloc(dd * 2);
  float* bqkv = (float*)alloc(NLAYER * QKV_LD * 4);
  float* hf   = (float*)alloc((size_t)MROWS * D_MODEL * 4);
  u16*   hb   = (u16*)  alloc((size_t)MROWS * D_MODEL * 2);
  u16*   qkvb = (u16*)  alloc((size_t)MROWS * QKV_LD * 2);   // 24 MB
  u16*   ob   = (u16*)  alloc((size_t)MROWS * D_MODEL * 2);  // 8 MB
  u16*   vt   = (u16*)  alloc((size_t)BATCH * NHEAD * DKH * SEQ * 2);
  u16*   tb   = (u16*)  alloc((size_t)MROWS * D_MODEL * 2);  // bf16 FFN2 out buffer
  u16*   mid  = qkvb;  // FFN mid [8192,2048] aliases qkvb+ob (dead by FFN1; stream-ordered)

  dim3 tb8(32, 8);
  transpose_cvt_kernel<<<dim3(16, 16, NLAYER), tb8, 0, stream>>>(Wq, wqkv_t,            512, 512,  dq, SCALE_LOG2E);
  transpose_cvt_kernel<<<dim3(16, 16, NLAYER), tb8, 0, stream>>>(Wk, wqkv_t + 512*512,  512, 512,  dq, 1.f);
  transpose_cvt_kernel<<<dim3(16, 16, NLAYER), tb8, 0, stream>>>(Wv, wqkv_t + 1024*512, 512, 512,  dq, 1.f);
  transpose_cvt_kernel<<<dim3(16, 16, NLAYER), tb8, 0, stream>>>(Wo, wo_t,   512, 512,  dd, 1.f);
  transpose_cvt_kernel<<<dim3(64, 16, NLAYER), tb8, 0, stream>>>(W1, w1_t,   512, 2048, df, 1.f);
  transpose_cvt_kernel<<<dim3(16, 64, NLAYER), tb8, 0, stream>>>(W2, w2_t,   2048, 512, df, 1.f);
  transpose_cvt_kernel<<<dim3(16, 16, 1),      tb8, 0, stream>>>(Wout, wout_t, 512, 512, dd, 1.f);
  concat_bias_kernel<<<NLAYER, 256, 0, stream>>>(bq, bk, bv, bqkv);

  embed_kernel<<<MROWS, 256, 0, stream>>>(ids, emb, pe, hf, hb);

  for (int l = 0; l < NLAYER; ++l) {
    gemm256_kernel<false, true><<<dim3(32, 6), 512, 131072, stream>>>(
        hb, wqkv_t + l * dq, bqkv + l * QKV_LD, qkvb, vt, MROWS, QKV_LD, 512);
    attn_mfma_kernel<<<1024, 256, 0, stream>>>(qkvb, vt, ob);
    gemm_ln_kernel<true><<<256, 512, 141568, stream>>>(
        ob, wo_t + l * dd, bo + l * 512, g1 + l * 512, be1 + l * 512,
        hf, hb, nullptr, 512);
    gemm256_kernel<true, false><<<dim3(32, 8), 512, 131072, stream>>>(
        hb, w1_t + l * df, b1 + l * 2048, mid, nullptr, MROWS, 2048, 512);
    gemm_kernel<64, false, false, true, false><<<dim3(128, 4), 256, 0, stream>>>(
        mid, w2_t + l * df, b2 + l * 512, nullptr, tb, nullptr, MROWS, 512, 2048);
    add_ln_kernel<<<MROWS, 256, 0, stream>>>(hf, tb, g2 + l * 512, be2 + l * 512, hf, hb);
  }
  gemm_ln_kernel<false><<<256, 512, 141568, stream>>>(
      hb, wout_t, bout, nullptr, nullptr, nullptr, nullptr, out, 512);
}